// Round 3
// baseline (637.761 us; speedup 1.0000x reference)
//
#include <hip/hip_runtime.h>
#include <hip/hip_bf16.h>
#include <math.h>

#define Bz 4
#define Sz 512
#define Dz 2048
#define NHz 8
#define DEGz 4
#define HDz 256
#define AHz 16
#define AHDz 128
#define SCALE_ATT 0.08838834764831845f  // 1/sqrt(128)

typedef __attribute__((ext_vector_type(8))) short short8;
typedef __attribute__((ext_vector_type(4))) float f32x4;

#define AS1 __attribute__((address_space(1)))
#define AS3 __attribute__((address_space(3)))

__device__ inline void gload16(const void* g, void* l) {
    __builtin_amdgcn_global_load_lds((const AS1 void*)g, (AS3 void*)l, 16, 0, 0);
}

// ---------------------------------------------------------------------------
// Multi-op GEMM/transpose dispatcher (legacy 128x128 structure).
// GEMM op: C[m][n] = sum_k A[m][k]*BT[n][k].
// flags: 1=bf16 out, 2=fp32 residual add, 4=score epilogue (scale+causal,
//        skip fully-masked tiles), 8=causal K-limit (kEnd=row0+128),
//        32=transpose+cvt op (A=fp32 src, C=bf16 dst)
struct GOp {
    const void* A; const void* B; void* C; const float* add;
    long long sAb, sAh, sBb, sBh, sCb, sCh;
    int K, lda, ldb, ldc, nbh, gx, gy, flags, tileEnd;
};
struct GArgs { int n; GOp op[6]; };

__global__ __launch_bounds__(256) void gemm_multi(GArgs ga) {
    __shared__ unsigned short As[2 * 128 * 32];
    __shared__ unsigned short Bs[2 * 128 * 32];

    int tid = blockIdx.x;
    int oi = 0;
    while (tid >= ga.op[oi].tileEnd) ++oi;
    GOp o = ga.op[oi];
    int local = tid - (oi ? ga.op[oi - 1].tileEnd : 0);
    int t = threadIdx.x;

    if (o.flags & 32) {
        // 32x32 transpose + fp32->bf16
        const float* src = (const float*)o.A;
        __hip_bfloat16* dst = (__hip_bfloat16*)o.C;
        int ty = local / o.gx, tx = local - ty * o.gx;
        int k0 = ty * 32, n0 = tx * 32;
        float* tile = (float*)As;  // [32][33]
        int c = t & 31, r8 = t >> 5;
#pragma unroll
        for (int p = 0; p < 4; ++p)
            tile[(r8 + p * 8) * 33 + c] = src[(long long)(k0 + r8 + p * 8) * o.lda + n0 + c];
        __syncthreads();
#pragma unroll
        for (int p = 0; p < 4; ++p)
            dst[(long long)(n0 + r8 + p * 8) * o.ldc + k0 + c] =
                __float2bfloat16(tile[c * 33 + r8 + p * 8]);
        return;
    }

    int perOp = o.gx * o.gy;
    int batch = local / perOp;
    int r3 = local - batch * perOp;
    int ty = r3 / o.gx;
    int tx = r3 - ty * o.gx;
    int row0 = ty * 128, col0 = tx * 128;

    if ((o.flags & 4) && (col0 > row0 + 127)) return;  // fully masked: softmax masks

    int zb = batch / o.nbh, zh = batch - zb * o.nbh;
    long long cb = (long long)zb * o.sCb + (long long)zh * o.sCh;

    int kEnd = o.K;
    if (o.flags & 8) { int ke = row0 + 128; kEnd = kEnd < ke ? kEnd : ke; }

    const unsigned short* Ab = (const unsigned short*)o.A + zb * o.sAb + zh * o.sAh;
    const unsigned short* Bb = (const unsigned short*)o.B + zb * o.sBb + zh * o.sBh;

    int w = t >> 6, l = t & 63;
    int lrow = l >> 2;
    int lchunk = (l & 3) * 8;

    const unsigned short* aP0 = Ab + (long long)(row0 + w * 16 + lrow) * o.lda + lchunk;
    const unsigned short* aP1 = aP0 + 64LL * o.lda;
    const unsigned short* bP0 = Bb + (long long)(col0 + w * 16 + lrow) * o.ldb + lchunk;
    const unsigned short* bP1 = bP0 + 64LL * o.ldb;
    unsigned short* aL0 = As + w * 512;
    unsigned short* aL1 = As + (w + 4) * 512;
    unsigned short* bL0 = Bs + w * 512;
    unsigned short* bL1 = Bs + (w + 4) * 512;

    int lm = l & 15, lq = l >> 4;
    int wr = (w >> 1) * 64, wc = (w & 1) * 64;

    f32x4 acc[4][4];
#pragma unroll
    for (int i = 0; i < 4; ++i)
#pragma unroll
        for (int j = 0; j < 4; ++j) acc[i][j] = (f32x4){0.f, 0.f, 0.f, 0.f};

    for (int k0 = 0; k0 < kEnd; k0 += 64) {
        gload16(aP0, aL0);
        gload16(aP1, aL1);
        gload16(bP0, bL0);
        gload16(bP1, bL1);
        gload16(aP0 + 32, aL0 + 4096);
        gload16(aP1 + 32, aL1 + 4096);
        gload16(bP0 + 32, bL0 + 4096);
        gload16(bP1 + 32, bL1 + 4096);
        aP0 += 64; aP1 += 64; bP0 += 64; bP1 += 64;
        __syncthreads();

#pragma unroll
        for (int h = 0; h < 2; ++h) {
            const unsigned short* Ah = As + h * 4096;
            const unsigned short* Bh = Bs + h * 4096;
            short8 af[4], bfr[4];
#pragma unroll
            for (int i = 0; i < 4; ++i)
                af[i] = *(const short8*)(Ah + (wr + i * 16 + lm) * 32 + lq * 8);
#pragma unroll
            for (int j = 0; j < 4; ++j)
                bfr[j] = *(const short8*)(Bh + (wc + j * 16 + lm) * 32 + lq * 8);
#pragma unroll
            for (int i = 0; i < 4; ++i)
#pragma unroll
                for (int j = 0; j < 4; ++j)
                    acc[i][j] = __builtin_amdgcn_mfma_f32_16x16x32_bf16(af[i], bfr[j], acc[i][j], 0, 0, 0);
        }
        __syncthreads();
    }

    if (o.flags & 1) {
        __hip_bfloat16* C = (__hip_bfloat16*)o.C;
#pragma unroll
        for (int i = 0; i < 4; ++i)
#pragma unroll
            for (int j = 0; j < 4; ++j)
#pragma unroll
                for (int r = 0; r < 4; ++r) {
                    int grow = row0 + wr + i * 16 + lq * 4 + r;
                    int gcol = col0 + wc + j * 16 + lm;
                    float v = acc[i][j][r];
                    if (o.flags & 4) v = (gcol > grow) ? -1e9f : v * SCALE_ATT;
                    C[cb + (long long)grow * o.ldc + gcol] = __float2bfloat16(v);
                }
    } else {
        float* C = (float*)o.C;
#pragma unroll
        for (int i = 0; i < 4; ++i)
#pragma unroll
            for (int j = 0; j < 4; ++j)
#pragma unroll
                for (int r = 0; r < 4; ++r) {
                    int grow = row0 + wr + i * 16 + lq * 4 + r;
                    int gcol = col0 + wc + j * 16 + lm;
                    float v = acc[i][j][r];
                    long long ci = cb + (long long)grow * o.ldc + gcol;
                    if (o.flags & 2) v += o.add[ci];
                    C[ci] = v;
                }
    }
}

// ---------------------------------------------------------------------------
// Deep-pipelined GEMM: 128x256 tile, BK=64, 512 threads (8 waves = 2Mx4N),
// double-buffered 96KB LDS, counted vmcnt (never 0 mid-loop), T2 XOR swizzle
// (pre-swizzled global source + swizzled ds_read; SQ_LDS_BANK_CONFLICT==0
// verified round 1). K-loop is a 4-phase fine interleave (m201 style): each
// phase = {ds_read subtile || 1-2 global_load_lds -> barrier -> lgkmcnt(0) ->
// setprio(1) 8 MFMA setprio(0) -> barrier}, so LDS-read time overlaps MFMA
// time across waves instead of serializing (2-phase measured 28% MfmaUtil vs
// ~46% LDS-bound ceiling of this geometry).
// flags: 1=bf16 out, 2=fp32 residual add. Requires M%128==0, N%256==0, K%64==0.
__global__ __launch_bounds__(512) void gemm_dp(GArgs ga) {
    __shared__ unsigned short As[2][128 * 64];   // 2 x 16KB
    __shared__ unsigned short Bs[2][256 * 64];   // 2 x 32KB

    int tid = blockIdx.x;
    int oi = 0;
    while (tid >= ga.op[oi].tileEnd) ++oi;
    GOp o = ga.op[oi];
    int local = tid - (oi ? ga.op[oi - 1].tileEnd : 0);
    int t = threadIdx.x;

    int perOp = o.gx * o.gy;
    int batch = local / perOp;
    int r3 = local - batch * perOp;
    int ty = r3 / o.gx, tx = r3 - ty * o.gx;
    int row0 = ty * 128, col0 = tx * 256;

    int zb = batch / o.nbh, zh = batch - zb * o.nbh;
    long long cb = (long long)zb * o.sCb + (long long)zh * o.sCh;

    const unsigned short* Ab = (const unsigned short*)o.A + zb * o.sAb + zh * o.sAh;
    const unsigned short* Bb = (const unsigned short*)o.B + zb * o.sBb + zh * o.sBh;

    int w = t >> 6, l = t & 63;
    // Stage addressing: LDS chunk (16B) index within a 64-row unit = w*64 + l.
    // row = w*8 + (l>>3); stored swizzled col = l&7; source col16 = (l&7)^(l>>3).
    // Permutation stays within each 128B row segment -> global reads coalesced.
    int srow = w * 8 + (l >> 3);
    int scol = ((l & 7) ^ (l >> 3)) << 3;   // shorts

    const unsigned short* aS0 = Ab + (long long)(row0 + srow) * o.lda + scol;
    const unsigned short* aS1 = Ab + (long long)(row0 + 64 + srow) * o.lda + scol;
    const unsigned short* bS0 = Bb + (long long)(col0 + srow) * o.ldb + scol;
    const unsigned short* bS1 = Bb + (long long)(col0 + 64 + srow) * o.ldb + scol;
    const unsigned short* bS2 = Bb + (long long)(col0 + 128 + srow) * o.ldb + scol;
    const unsigned short* bS3 = Bb + (long long)(col0 + 192 + srow) * o.ldb + scol;

    int wofs = w * 512;  // shorts; HW adds lane*16B

    // prologue: stage K-tile 0 into buffer 0 (6 load-units)
    gload16(aS0, &As[0][wofs]);
    gload16(aS1, &As[0][4096 + wofs]);
    gload16(bS0, &Bs[0][wofs]);
    gload16(bS1, &Bs[0][4096 + wofs]);
    gload16(bS2, &Bs[0][8192 + wofs]);
    gload16(bS3, &Bs[0][12288 + wofs]);
    aS0 += 64; aS1 += 64; bS0 += 64; bS1 += 64; bS2 += 64; bS3 += 64;

    int lm = l & 15, lq = l >> 4;
    int wr = w >> 2, wc = w & 3;
    // swizzled k-chunk offsets for the two K-halves (row&7 == lm&7 since frag
    // base rows are multiples of 16)
    int c0 = ((lq) ^ (lm & 7)) << 3;
    int c1 = ((4 + lq) ^ (lm & 7)) << 3;

    f32x4 acc[4][4];
#pragma unroll
    for (int i = 0; i < 4; ++i)
#pragma unroll
        for (int j = 0; j < 4; ++j) acc[i][j] = (f32x4){0.f, 0.f, 0.f, 0.f};

    int nkt = o.K >> 6;
    for (int kt = 0; kt < nkt; ++kt) {
        unsigned short* Ac = &As[kt & 1][0];
        unsigned short* Bc = &Bs[kt & 1][0];
        unsigned short* An = &As[(kt & 1) ^ 1][0];
        unsigned short* Bn = &Bs[(kt & 1) ^ 1][0];
        bool pf = (kt + 1 < nkt);

        // issue first 2 units of next tile, counted wait for current tile's 6
        if (pf) {
            gload16(aS0, An + wofs);
            gload16(aS1, An + 4096 + wofs);
        }
        __builtin_amdgcn_sched_barrier(0);
        if (pf) asm volatile("s_waitcnt vmcnt(2)" ::: "memory");
        else    asm volatile("s_waitcnt vmcnt(0)" ::: "memory");
        __builtin_amdgcn_s_barrier();
        __builtin_amdgcn_sched_barrier(0);

        short8 aR0[2][2], aR1[2][2], bR0[2][2], bR1[2][2];

        // ---- P0: reads A(mi 0-1) + B(nj 0-1); 1 gload; 8 MFMA ----
#pragma unroll
        for (int mi = 0; mi < 2; ++mi) {
            const unsigned short* ar = Ac + (wr * 64 + mi * 16 + lm) * 64;
            aR0[mi][0] = *(const short8*)(ar + c0);
            aR0[mi][1] = *(const short8*)(ar + c1);
        }
#pragma unroll
        for (int nj = 0; nj < 2; ++nj) {
            const unsigned short* br = Bc + (wc * 64 + nj * 16 + lm) * 64;
            bR0[nj][0] = *(const short8*)(br + c0);
            bR0[nj][1] = *(const short8*)(br + c1);
        }
        if (pf) gload16(bS0, Bn + wofs);
        __builtin_amdgcn_s_barrier();
        asm volatile("s_waitcnt lgkmcnt(0)" ::: "memory");
        __builtin_amdgcn_sched_barrier(0);
        __builtin_amdgcn_s_setprio(1);
#pragma unroll
        for (int kh = 0; kh < 2; ++kh)
#pragma unroll
            for (int mi = 0; mi < 2; ++mi)
#pragma unroll
                for (int nj = 0; nj < 2; ++nj)
                    acc[mi][nj] = __builtin_amdgcn_mfma_f32_16x16x32_bf16(aR0[mi][kh], bR0[nj][kh], acc[mi][nj], 0, 0, 0);
        __builtin_amdgcn_s_setprio(0);
        __builtin_amdgcn_s_barrier();

        // ---- P1: reads B(nj 2-3); 1 gload; 8 MFMA ----
#pragma unroll
        for (int nj = 0; nj < 2; ++nj) {
            const unsigned short* br = Bc + (wc * 64 + (nj + 2) * 16 + lm) * 64;
            bR1[nj][0] = *(const short8*)(br + c0);
            bR1[nj][1] = *(const short8*)(br + c1);
        }
        if (pf) gload16(bS1, Bn + 4096 + wofs);
        __builtin_amdgcn_s_barrier();
        asm volatile("s_waitcnt lgkmcnt(0)" ::: "memory");
        __builtin_amdgcn_sched_barrier(0);
        __builtin_amdgcn_s_setprio(1);
#pragma unroll
        for (int kh = 0; kh < 2; ++kh)
#pragma unroll
            for (int mi = 0; mi < 2; ++mi)
#pragma unroll
                for (int nj = 0; nj < 2; ++nj)
                    acc[mi][nj + 2] = __builtin_amdgcn_mfma_f32_16x16x32_bf16(aR0[mi][kh], bR1[nj][kh], acc[mi][nj + 2], 0, 0, 0);
        __builtin_amdgcn_s_setprio(0);
        __builtin_amdgcn_s_barrier();

        // ---- P2: reads A(mi 2-3); 2 gloads; 8 MFMA ----
#pragma unroll
        for (int mi = 0; mi < 2; ++mi) {
            const unsigned short* ar = Ac + (wr * 64 + (mi + 2) * 16 + lm) * 64;
            aR1[mi][0] = *(const short8*)(ar + c0);
            aR1[mi][1] = *(const short8*)(ar + c1);
        }
        if (pf) {
            gload16(bS2, Bn + 8192 + wofs);
            gload16(bS3, Bn + 12288 + wofs);
            aS0 += 64; aS1 += 64; bS0 += 64; bS1 += 64; bS2 += 64; bS3 += 64;
        }
        __builtin_amdgcn_s_barrier();
        asm volatile("s_waitcnt lgkmcnt(0)" ::: "memory");
        __builtin_amdgcn_sched_barrier(0);
        __builtin_amdgcn_s_setprio(1);
#pragma unroll
        for (int kh = 0; kh < 2; ++kh)
#pragma unroll
            for (int mi = 0; mi < 2; ++mi)
#pragma unroll
                for (int nj = 0; nj < 2; ++nj)
                    acc[mi + 2][nj] = __builtin_amdgcn_mfma_f32_16x16x32_bf16(aR1[mi][kh], bR0[nj][kh], acc[mi + 2][nj], 0, 0, 0);
        __builtin_amdgcn_s_setprio(0);
        __builtin_amdgcn_s_barrier();

        // ---- P3: no reads; 8 MFMA; end-of-tile barrier ----
        __builtin_amdgcn_s_setprio(1);
#pragma unroll
        for (int kh = 0; kh < 2; ++kh)
#pragma unroll
            for (int mi = 0; mi < 2; ++mi)
#pragma unroll
                for (int nj = 0; nj < 2; ++nj)
                    acc[mi + 2][nj + 2] = __builtin_amdgcn_mfma_f32_16x16x32_bf16(aR1[mi][kh], bR1[nj][kh], acc[mi + 2][nj + 2], 0, 0, 0);
        __builtin_amdgcn_s_setprio(0);
        __builtin_amdgcn_sched_barrier(0);
        __builtin_amdgcn_s_barrier();   // all reads of buf cur done; restage next iter
        __builtin_amdgcn_sched_barrier(0);
    }

    if (o.flags & 1) {
        __hip_bfloat16* C = (__hip_bfloat16*)o.C;
#pragma unroll
        for (int i = 0; i < 4; ++i)
#pragma unroll
            for (int j = 0; j < 4; ++j)
#pragma unroll
                for (int r = 0; r < 4; ++r) {
                    int grow = row0 + wr * 64 + i * 16 + lq * 4 + r;
                    int gcol = col0 + wc * 64 + j * 16 + lm;
                    C[cb + (long long)grow * o.ldc + gcol] = __float2bfloat16(acc[i][j][r]);
                }
    } else {
        float* C = (float*)o.C;
#pragma unroll
        for (int i = 0; i < 4; ++i)
#pragma unroll
            for (int j = 0; j < 4; ++j)
#pragma unroll
                for (int r = 0; r < 4; ++r) {
                    int grow = row0 + wr * 64 + i * 16 + lq * 4 + r;
                    int gcol = col0 + wc * 64 + j * 16 + lm;
                    float v = acc[i][j][r];
                    long long ci = cb + (long long)grow * o.ldc + gcol;
                    if (o.flags & 2) v += o.add[ci];
                    C[ci] = v;
                }
    }
}

// ---------------------------------------------------------------------------
// rmsnorm (fp32 in, bf16 out), one block per row
__global__ __launch_bounds__(256) void rmsnorm_kernel(const float* __restrict__ x,
                                                      const float* __restrict__ w,
                                                      __hip_bfloat16* __restrict__ out) {
    long long base = (long long)blockIdx.x * Dz;
    int t = threadIdx.x;
    float v[8];
    float ss = 0.f;
#pragma unroll
    for (int p = 0; p < 8; ++p) { v[p] = x[base + t + p * 256]; ss += v[p] * v[p]; }
    __shared__ float red[256];
    red[t] = ss; __syncthreads();
    for (int s2 = 128; s2 > 0; s2 >>= 1) { if (t < s2) red[t] += red[t + s2]; __syncthreads(); }
    float sc = rsqrtf(red[0] / (float)Dz + 1e-6f);
#pragma unroll
    for (int p = 0; p < 8; ++p) { int c = t + p * 256; out[base + c] = __float2bfloat16(v[p] * sc * w[c]); }
}

// xmean phase 1: partial sums over 64-row chunks. grid = B*8sc*8dc = 256
__global__ __launch_bounds__(256) void xmean_p1(const __hip_bfloat16* __restrict__ xn,
                                                float* __restrict__ xmp) {
    int blk = blockIdx.x;
    int b = blk >> 6, sc = (blk >> 3) & 7, dc = blk & 7;
    int t = threadIdx.x;
    int d = dc * 256 + t;
    const __hip_bfloat16* p = xn + (long long)b * Sz * Dz + (long long)sc * 64 * Dz + d;
    float s = 0.f;
    for (int si = 0; si < 64; ++si) s += __bfloat162float(p[(long long)si * Dz]);
    xmp[(b * 8 + sc) * Dz + d] = s;
}

// mlp1 with integrated mean-reduction: h[b,j]=silu(xm@wc1+bc1). grid = B*16 = 64
__global__ __launch_bounds__(256) void mlp1_kernel(const float* __restrict__ xmp,
                                                   const float* __restrict__ wc1,
                                                   const float* __restrict__ bc1,
                                                   float* __restrict__ h) {
    int blk = blockIdx.x;
    int b = blk >> 4, jb = blk & 15;
    int t = threadIdx.x;
    __shared__ float xs[Dz];
    __shared__ float red[8][32];
    const float* P = xmp + b * 8 * Dz;
#pragma unroll
    for (int p = 0; p < 8; ++p) {
        int d = t + p * 256;
        float s = 0.f;
#pragma unroll
        for (int q = 0; q < 8; ++q) s += P[q * Dz + d];
        xs[d] = s * (1.0f / (float)Sz);
    }
    __syncthreads();
    int j = jb * 32 + (t & 31), ksl = t >> 5;
    float s = 0.f;
    for (int k = ksl * 256; k < ksl * 256 + 256; ++k)
        s += xs[k] * wc1[(long long)k * 512 + j];
    red[ksl][t & 31] = s;
    __syncthreads();
    if (t < 32) {
        float tot = 0.f;
#pragma unroll
        for (int q = 0; q < 8; ++q) tot += red[q][t];
        tot += bc1[jb * 32 + t];
        h[b * 512 + jb * 32 + t] = tot / (1.0f + expf(-tot));
    }
}

// coeffs with k-split. grid = B*128 = 512
__global__ __launch_bounds__(256) void coeffs_kernel(const float* __restrict__ h,
                                                     const float* __restrict__ wc2,
                                                     const float* __restrict__ bc2,
                                                     float* __restrict__ coeffs) {
    int blk = blockIdx.x;
    int b = blk >> 7, ib = blk & 127;
    int t = threadIdx.x;
    int i = ib * 64 + (t & 63), ksl = t >> 6;
    const float* hb = h + b * 512;
    float s = 0.f;
    for (int k = ksl * 128; k < ksl * 128 + 128; ++k)
        s += hb[k] * wc2[(long long)k * 8192 + i];
    __shared__ float red[4][64];
    red[ksl][t & 63] = s;
    __syncthreads();
    if (t < 64) {
        int ii = ib * 64 + t;
        float tot = red[0][t] + red[1][t] + red[2][t] + red[3][t] + bc2[ii];
        int kdeg = (ii >> 8) & 3;
        coeffs[b * 8192 + ii] = tot * (0.1f / (float)(kdeg + 1));
    }
}

// Chebyshev path; xn bf16 in, cheby/kv bf16 out
__global__ __launch_bounds__(256) void cheby_kernel(const __hip_bfloat16* __restrict__ xn,
                                                    const float* __restrict__ coeffs,
                                                    __hip_bfloat16* __restrict__ cheby_out,
                                                    __hip_bfloat16* __restrict__ kv_src) {
    int bs = blockIdx.x;
    int b = bs >> 9;
    long long base = (long long)bs * Dz;
    int t = threadIdx.x;
    __shared__ float xrow[Dz];
    __shared__ float hsum[NHz][33];
    __shared__ float T[NHz][4];
#pragma unroll
    for (int p = 0; p < 8; ++p) xrow[t + p * 256] = __bfloat162float(xn[base + t + p * 256]);
    __syncthreads();
    int hh = t >> 5, lane = t & 31;
    float s = 0.f;
#pragma unroll
    for (int q = 0; q < 8; ++q) s += xrow[hh * HDz + lane + q * 32];
    hsum[hh][lane] = s;
    __syncthreads();
    if (t < NHz) {
        float tot = 0.f;
        for (int l2 = 0; l2 < 32; ++l2) tot += hsum[t][l2];
        float z = tanhf(tot / (float)HDz);
        float t2 = 2.f * z * z - 1.f;
        T[t][0] = 1.f; T[t][1] = z; T[t][2] = t2; T[t][3] = 2.f * z * t2 - z;
    }
    __syncthreads();
    const float* cbp = coeffs + (long long)b * (NHz * DEGz * HDz);
#pragma unroll
    for (int p = 0; p < 8; ++p) {
        int e = t + p * 256;
        int hd = e >> 8;
        int d = e & (HDz - 1);
        const float* ch = cbp + hd * (DEGz * HDz) + d;
        float co = T[hd][0] * ch[0] + T[hd][1] * ch[HDz] + T[hd][2] * ch[2 * HDz] + T[hd][3] * ch[3 * HDz];
        cheby_out[base + e] = __float2bfloat16(co);
        kv_src[base + e] = __float2bfloat16(xrow[e] + co);
    }
}

// softmax over 512-wide bf16 rows; applies causal mask itself
__global__ __launch_bounds__(128) void softmax_kernel(__hip_bfloat16* __restrict__ sc) {
    long long rid = blockIdx.x;
    int i = (int)(rid & (Sz - 1));
    long long base = rid * Sz;
    int t = threadIdx.x;
    float vals[4];
    float mx = -1e30f;
#pragma unroll
    for (int p = 0; p < 4; ++p) {
        int j = t + p * 128;
        float v = __bfloat162float(sc[base + j]);
        if (j > i) v = -1e9f;
        vals[p] = v;
        mx = fmaxf(mx, v);
    }
    __shared__ float red[128];
    red[t] = mx; __syncthreads();
    for (int s2 = 64; s2 > 0; s2 >>= 1) { if (t < s2) red[t] = fmaxf(red[t], red[t + s2]); __syncthreads(); }
    mx = red[0]; __syncthreads();
    float sum = 0.f;
#pragma unroll
    for (int p = 0; p < 4; ++p) { vals[p] = __expf(vals[p] - mx); sum += vals[p]; }
    red[t] = sum; __syncthreads();
    for (int s2 = 64; s2 > 0; s2 >>= 1) { if (t < s2) red[t] += red[t + s2]; __syncthreads(); }
    float inv = 1.0f / red[0];
#pragma unroll
    for (int p = 0; p < 4; ++p) sc[base + t + p * 128] = __float2bfloat16(vals[p] * inv);
}

// hcat = [rmsnorm(cheby,w_nc), rmsnorm(slr,w_ns)]
__global__ __launch_bounds__(256) void hcat_kernel(const __hip_bfloat16* __restrict__ cheby,
                                                   const __hip_bfloat16* __restrict__ slr,
                                                   const float* __restrict__ w_nc,
                                                   const float* __restrict__ w_ns,
                                                   __hip_bfloat16* __restrict__ hcat) {
    long long row = blockIdx.x;
    const __hip_bfloat16* c = cheby + row * Dz;
    const __hip_bfloat16* sl = slr + row * Dz;
    __hip_bfloat16* o = hcat + row * (2 * Dz);
    int t = threadIdx.x;
    float v1[8], v2[8];
    float ss1 = 0.f, ss2 = 0.f;
#pragma unroll
    for (int p = 0; p < 8; ++p) {
        v1[p] = __bfloat162float(c[t + p * 256]);  ss1 += v1[p] * v1[p];
        v2[p] = __bfloat162float(sl[t + p * 256]); ss2 += v2[p] * v2[p];
    }
    __shared__ float red[256];
    red[t] = ss1; __syncthreads();
    for (int s2 = 128; s2 > 0; s2 >>= 1) { if (t < s2) red[t] += red[t + s2]; __syncthreads(); }
    float sc1 = rsqrtf(red[0] / (float)Dz + 1e-6f);
    __syncthreads();
    red[t] = ss2; __syncthreads();
    for (int s2 = 128; s2 > 0; s2 >>= 1) { if (t < s2) red[t] += red[t + s2]; __syncthreads(); }
    float sc2 = rsqrtf(red[0] / (float)Dz + 1e-6f);
#pragma unroll
    for (int p = 0; p < 8; ++p) {
        int cx = t + p * 256;
        o[cx] = __float2bfloat16(v1[p] * sc1 * w_nc[cx]);
        o[Dz + cx] = __float2bfloat16(v2[p] * sc2 * w_ns[cx]);
    }
}

// fused = rmsnorm(silu(gate)*value, w_np) — from bf16 gv
__global__ __launch_bounds__(256) void fusedgate_kernel(const __hip_bfloat16* __restrict__ gv,
                                                        const float* __restrict__ w_np,
                                                        __hip_bfloat16* __restrict__ fused) {
    long long row = blockIdx.x;
    const __hip_bfloat16* g = gv + row * (2 * Dz);
    __hip_bfloat16* o = fused + row * Dz;
    int t = threadIdx.x;
    float f[8];
    float ss = 0.f;
#pragma unroll
    for (int p = 0; p < 8; ++p) {
        float ga = __bfloat162float(g[t + p * 256]);
        float va = __bfloat162float(g[Dz + t + p * 256]);
        float sv = ga / (1.0f + expf(-ga)) * va;
        f[p] = sv; ss += sv * sv;
    }
    __shared__ float red[256];
    red[t] = ss; __syncthreads();
    for (int s2 = 128; s2 > 0; s2 >>= 1) { if (t < s2) red[t] += red[t + s2]; __syncthreads(); }
    float sc = rsqrtf(red[0] / (float)Dz + 1e-6f);
#pragma unroll
    for (int p = 0; p < 8; ++p) { int cx = t + p * 256; o[cx] = __float2bfloat16(f[p] * sc * w_np[cx]); }
}

// ---------------------------------------------------------------------------
static GOp gop(const void* A, const void* B, void* C, const float* add,
               int K, int lda, int ldb, int ldc, int nbh, int nb, int gx, int gy,
               long long sAb, long long sAh, long long sBb, long long sBh,
               long long sCb, long long sCh, int flags) {
    GOp o;
    o.A = A; o.B = B; o.C = C; o.add = add;
    o.sAb = sAb; o.sAh = sAh; o.sBb = sBb; o.sBh = sBh; o.sCb = sCb; o.sCh = sCh;
    o.K = K; o.lda = lda; o.ldb = ldb; o.ldc = ldc; o.nbh = nbh;
    o.gx = gx; o.gy = gy; o.flags = flags;
    o.tileEnd = (flags & 32) ? gx * gy : nb * gx * gy;  // count; prefixed later
    return o;
}

static void launch_multi(hipStream_t st, GOp* ops, int n) {
    GArgs ga; ga.n = n;
    int acc = 0;
    for (int i = 0; i < n; ++i) { acc += ops[i].tileEnd; ga.op[i] = ops[i]; ga.op[i].tileEnd = acc; }
    hipLaunchKernelGGL(gemm_multi, dim3(acc), dim3(256), 0, st, ga);
}

static void launch_dp(hipStream_t st, GOp* ops, int n) {
    GArgs ga; ga.n = n;
    int acc = 0;
    for (int i = 0; i < n; ++i) { acc += ops[i].tileEnd; ga.op[i] = ops[i]; ga.op[i].tileEnd = acc; }
    hipLaunchKernelGGL(gemm_dp, dim3(acc), dim3(512), 0, st, ga);
}

extern "C" void kernel_launch(void* const* d_in, const int* in_sizes, int n_in,
                              void* d_out, int out_size, void* d_ws, size_t ws_size,
                              hipStream_t stream) {
    const float* x     = (const float*)d_in[0];
    const float* w_in  = (const float*)d_in[1];
    const float* wc1   = (const float*)d_in[6];
    const float* bc1   = (const float*)d_in[7];
    const float* wc2   = (const float*)d_in[8];
    const float* bc2   = (const float*)d_in[9];
    const float* wq    = (const float*)d_in[10];
    const float* wk    = (const float*)d_in[11];
    const float* wv    = (const float*)d_in[12];
    const float* wo    = (const float*)d_in[13];
    const float* w_nc  = (const float*)d_in[14];
    const float* w_ns  = (const float*)d_in[15];
    const float* w_fgv = (const float*)d_in[16];
    const float* w_np  = (const float*)d_in[17];
    const float* w_out = (const float*)d_in[18];
    float* out = (float*)d_out;

    const size_t MB = 1ull << 20;
    char* W = (char*)d_ws;
    __hip_bfloat16* xn_bf    = (__hip_bfloat16*)(W + 0 * MB);
    __hip_bfloat16* kv_bf    = (__hip_bfloat16*)(W + 8 * MB);
    __hip_bfloat16* cheby_bf = (__hip_bfloat16*)(W + 16 * MB);
    __hip_bfloat16* q_bf     = (__hip_bfloat16*)(W + 24 * MB);
    __hip_bfloat16* k_bf     = (__hip_bfloat16*)(W + 32 * MB);
    __hip_bfloat16* vT_bf    = (__hip_bfloat16*)(W + 40 * MB);
    __hip_bfloat16* o_bf     = (__hip_bfloat16*)(W + 48 * MB);
    __hip_bfloat16* scores   = (__hip_bfloat16*)(W + 56 * MB);   // 32MB
    __hip_bfloat16* wq_t     = (__hip_bfloat16*)(W + 88 * MB);
    __hip_bfloat16* wk_t     = (__hip_bfloat16*)(W + 96 * MB);
    __hip_bfloat16* wv_t     = (__hip_bfloat16*)(W + 104 * MB);
    __hip_bfloat16* wo_t     = (__hip_bfloat16*)(W + 112 * MB);
    __hip_bfloat16* wout_t   = (__hip_bfloat16*)(W + 120 * MB);
    // lifetime reuse (scores region becomes wfgv_t only AFTER PV has consumed it)
    __hip_bfloat16* wfgv_t   = (__hip_bfloat16*)(W + 56 * MB);
    __hip_bfloat16* slr_bf   = (__hip_bfloat16*)(W + 0 * MB);    // xn dead
    __hip_bfloat16* hcat_bf  = (__hip_bfloat16*)(W + 24 * MB);   // q,k dead (16MB)
    __hip_bfloat16* gv_bf    = (__hip_bfloat16*)(W + 40 * MB);   // vT,o dead (16MB)
    __hip_bfloat16* fused_bf = (__hip_bfloat16*)(W + 8 * MB);    // kv dead
    float* xmp   = (float*)(W + 128 * MB);                       // 8*B*D
    float* hbuf  = xmp + 65536;
    float* cbuf  = hbuf + 2048;

    const int BS = Bz * Sz;
    const long long SD = (long long)Sz * Dz;
    const long long SS = (long long)Sz * Sz;

    // L1: five 2048x2048 weight transposes in one launch
    {
        GOp ops[5];
        const float* srcs[5] = {wq, wk, wv, wo, w_out};
        __hip_bfloat16* dsts[5] = {wq_t, wk_t, wv_t, wo_t, wout_t};
        for (int i = 0; i < 5; ++i)
            ops[i] = gop(srcs[i], nullptr, dsts[i], nullptr, Dz, Dz, 0, Dz,
                         1, 1, 64, 64, 0, 0, 0, 0, 0, 0, 32);
        launch_multi(stream, ops, 5);
    }
    // L2: xn = rmsnorm(x)
    hipLaunchKernelGGL(rmsnorm_kernel, dim3(BS), dim3(256), 0, stream, x, w_in, xn_bf);
    // L3-L5: coeff path
    hipLaunchKernelGGL(xmean_p1, dim3(256), dim3(256), 0, stream, xn_bf, xmp);
    hipLaunchKernelGGL(mlp1_kernel, dim3(64), dim3(256), 0, stream, xmp, wc1, bc1, hbuf);
    hipLaunchKernelGGL(coeffs_kernel, dim3(512), dim3(256), 0, stream, hbuf, wc2, bc2, cbuf);
    // L6: cheby + kv_src
    hipLaunchKernelGGL(cheby_kernel, dim3(BS), dim3(256), 0, stream, xn_bf, cbuf, cheby_bf, kv_bf);
    // L7: q, k, vT via deep-pipelined GEMM (384 blocks)
    {
        GOp ops[3];
        ops[0] = gop(xn_bf, wq_t, q_bf, nullptr, Dz, Dz, Dz, Dz, 1, 1, 8, 16,
                     0, 0, 0, 0, 0, 0, 1);
        ops[1] = gop(kv_bf, wk_t, k_bf, nullptr, Dz, Dz, Dz, Dz, 1, 1, 8, 16,
                     0, 0, 0, 0, 0, 0, 1);
        ops[2] = gop(wv_t, kv_bf, vT_bf, nullptr, Dz, Dz, Dz, Sz, 1, Bz, 2, 16,
                     0, 0, SD, 0, (long long)Dz * Sz, 0, 1);
        launch_dp(stream, ops, 3);
    }
    // L8: scores = q@k^T, scale+mask epilogue, skip masked tiles (legacy kernel)
    {
        GOp op = gop(q_bf, k_bf, scores, nullptr, AHDz, Dz, Dz, Sz, AHz, Bz * AHz, 4, 4,
                     SD, AHDz, SD, AHDz, (long long)AHz * SS, SS, 1 | 4);
        launch_multi(stream, &op, 1);
    }
    // L9: softmax (applies causal mask)
    hipLaunchKernelGGL(softmax_kernel, dim3(Bz * AHz * Sz), dim3(128), 0, stream, scores);
    // L10: PV alone (reads scores — nothing may write the scores region here!)
    {
        GOp op = gop(scores, vT_bf, o_bf, nullptr, Sz, Sz, Sz, Dz, AHz, Bz * AHz, 1, 4,
                     (long long)AHz * SS, SS, (long long)Dz * Sz, 128LL * Sz,
                     SD, 128, 1 | 8);
        launch_multi(stream, &op, 1);
    }
    // L11: slr = o @ wo (legacy, full-chip 256 blocks) + wfgv transpose in ONE
    // launch so the memory-bound transpose overlaps the compute-bound GEMM
    {
        GOp ops[2];
        ops[0] = gop(o_bf, wo_t, slr_bf, nullptr, Dz, Dz, Dz, Dz, 1, 1, 16, 16,
                     0, 0, 0, 0, 0, 0, 1);
        ops[1] = gop(w_fgv, nullptr, wfgv_t, nullptr, 2 * Dz, 2 * Dz, 0, 2 * Dz,
                     1, 1, 128, 128, 0, 0, 0, 0, 0, 0, 32);
        launch_multi(stream, ops, 2);
    }
    // L12: hcat
    hipLaunchKernelGGL(hcat_kernel, dim3(BS), dim3(256), 0, stream, cheby_bf, slr_bf, w_nc, w_ns, hcat_bf);
    // L13: gv = hcat @ w_fgv (deep-pipelined, 256 blocks = exact chip fill)
    {
        GOp op = gop(hcat_bf, wfgv_t, gv_bf, nullptr, 2 * Dz, 2 * Dz, 2 * Dz, 2 * Dz,
                     1, 1, 16, 16, 0, 0, 0, 0, 0, 0, 1);
        launch_dp(stream, &op, 1);
    }
    // L14: fused gate
    hipLaunchKernelGGL(fusedgate_kernel, dim3(BS), dim3(256), 0, stream, gv_bf, w_np, fused_bf);
    // L15: out = x + fused @ w_out (legacy, full-chip 256 blocks)
    {
        GOp op = gop(fused_bf, wout_t, out, x, Dz, Dz, Dz, Dz, 1, 1, 16, 16,
                     0, 0, 0, 0, 0, 0, 2);
        launch_multi(stream, &op, 1);
    }
}

// Round 4
// 585.525 us; speedup vs baseline: 1.0892x; 1.0892x over previous
//
#include <hip/hip_runtime.h>
#include <hip/hip_bf16.h>
#include <math.h>

#define Bz 4
#define Sz 512
#define Dz 2048
#define NHz 8
#define DEGz 4
#define HDz 256
#define AHz 16
#define AHDz 128
#define SCALE_ATT 0.08838834764831845f  // 1/sqrt(128)

typedef __attribute__((ext_vector_type(8))) short short8;
typedef __attribute__((ext_vector_type(4))) float f32x4;

#define AS1 __attribute__((address_space(1)))
#define AS3 __attribute__((address_space(3)))

__device__ inline void gload16(const void* g, void* l) {
    __builtin_amdgcn_global_load_lds((const AS1 void*)g, (AS3 void*)l, 16, 0, 0);
}

// ---------------------------------------------------------------------------
// Multi-op GEMM/transpose dispatcher (legacy 128x128 structure).
// GEMM op: C[m][n] = sum_k A[m][k]*BT[n][k].
// flags: 1=bf16 out, 2=fp32 residual add, 4=score epilogue (scale+causal,
//        skip fully-masked tiles), 8=causal K-limit (kEnd=row0+128),
//        32=transpose+cvt op (A=fp32 src, C=bf16 dst)
struct GOp {
    const void* A; const void* B; void* C; const float* add;
    long long sAb, sAh, sBb, sBh, sCb, sCh;
    int K, lda, ldb, ldc, nbh, gx, gy, flags, tileEnd;
};
struct GArgs { int n; GOp op[6]; };

__global__ __launch_bounds__(256) void gemm_multi(GArgs ga) {
    __shared__ unsigned short As[2 * 128 * 32];
    __shared__ unsigned short Bs[2 * 128 * 32];

    int tid = blockIdx.x;
    int oi = 0;
    while (tid >= ga.op[oi].tileEnd) ++oi;
    GOp o = ga.op[oi];
    int local = tid - (oi ? ga.op[oi - 1].tileEnd : 0);
    int t = threadIdx.x;

    if (o.flags & 32) {
        // 32x32 transpose + fp32->bf16
        const float* src = (const float*)o.A;
        __hip_bfloat16* dst = (__hip_bfloat16*)o.C;
        int ty = local / o.gx, tx = local - ty * o.gx;
        int k0 = ty * 32, n0 = tx * 32;
        float* tile = (float*)As;  // [32][33]
        int c = t & 31, r8 = t >> 5;
#pragma unroll
        for (int p = 0; p < 4; ++p)
            tile[(r8 + p * 8) * 33 + c] = src[(long long)(k0 + r8 + p * 8) * o.lda + n0 + c];
        __syncthreads();
#pragma unroll
        for (int p = 0; p < 4; ++p)
            dst[(long long)(n0 + r8 + p * 8) * o.ldc + k0 + c] =
                __float2bfloat16(tile[c * 33 + r8 + p * 8]);
        return;
    }

    int perOp = o.gx * o.gy;
    int batch = local / perOp;
    int r3 = local - batch * perOp;
    int ty = r3 / o.gx;
    int tx = r3 - ty * o.gx;
    int row0 = ty * 128, col0 = tx * 128;

    if ((o.flags & 4) && (col0 > row0 + 127)) return;  // fully masked: softmax masks

    int zb = batch / o.nbh, zh = batch - zb * o.nbh;
    long long cb = (long long)zb * o.sCb + (long long)zh * o.sCh;

    int kEnd = o.K;
    if (o.flags & 8) { int ke = row0 + 128; kEnd = kEnd < ke ? kEnd : ke; }

    const unsigned short* Ab = (const unsigned short*)o.A + zb * o.sAb + zh * o.sAh;
    const unsigned short* Bb = (const unsigned short*)o.B + zb * o.sBb + zh * o.sBh;

    int w = t >> 6, l = t & 63;
    int lrow = l >> 2;
    int lchunk = (l & 3) * 8;

    const unsigned short* aP0 = Ab + (long long)(row0 + w * 16 + lrow) * o.lda + lchunk;
    const unsigned short* aP1 = aP0 + 64LL * o.lda;
    const unsigned short* bP0 = Bb + (long long)(col0 + w * 16 + lrow) * o.ldb + lchunk;
    const unsigned short* bP1 = bP0 + 64LL * o.ldb;
    unsigned short* aL0 = As + w * 512;
    unsigned short* aL1 = As + (w + 4) * 512;
    unsigned short* bL0 = Bs + w * 512;
    unsigned short* bL1 = Bs + (w + 4) * 512;

    int lm = l & 15, lq = l >> 4;
    int wr = (w >> 1) * 64, wc = (w & 1) * 64;

    f32x4 acc[4][4];
#pragma unroll
    for (int i = 0; i < 4; ++i)
#pragma unroll
        for (int j = 0; j < 4; ++j) acc[i][j] = (f32x4){0.f, 0.f, 0.f, 0.f};

    for (int k0 = 0; k0 < kEnd; k0 += 64) {
        gload16(aP0, aL0);
        gload16(aP1, aL1);
        gload16(bP0, bL0);
        gload16(bP1, bL1);
        gload16(aP0 + 32, aL0 + 4096);
        gload16(aP1 + 32, aL1 + 4096);
        gload16(bP0 + 32, bL0 + 4096);
        gload16(bP1 + 32, bL1 + 4096);
        aP0 += 64; aP1 += 64; bP0 += 64; bP1 += 64;
        __syncthreads();

#pragma unroll
        for (int h = 0; h < 2; ++h) {
            const unsigned short* Ah = As + h * 4096;
            const unsigned short* Bh = Bs + h * 4096;
            short8 af[4], bfr[4];
#pragma unroll
            for (int i = 0; i < 4; ++i)
                af[i] = *(const short8*)(Ah + (wr + i * 16 + lm) * 32 + lq * 8);
#pragma unroll
            for (int j = 0; j < 4; ++j)
                bfr[j] = *(const short8*)(Bh + (wc + j * 16 + lm) * 32 + lq * 8);
#pragma unroll
            for (int i = 0; i < 4; ++i)
#pragma unroll
                for (int j = 0; j < 4; ++j)
                    acc[i][j] = __builtin_amdgcn_mfma_f32_16x16x32_bf16(af[i], bfr[j], acc[i][j], 0, 0, 0);
        }
        __syncthreads();
    }

    if (o.flags & 1) {
        __hip_bfloat16* C = (__hip_bfloat16*)o.C;
#pragma unroll
        for (int i = 0; i < 4; ++i)
#pragma unroll
            for (int j = 0; j < 4; ++j)
#pragma unroll
                for (int r = 0; r < 4; ++r) {
                    int grow = row0 + wr + i * 16 + lq * 4 + r;
                    int gcol = col0 + wc + j * 16 + lm;
                    float v = acc[i][j][r];
                    if (o.flags & 4) v = (gcol > grow) ? -1e9f : v * SCALE_ATT;
                    C[cb + (long long)grow * o.ldc + gcol] = __float2bfloat16(v);
                }
    } else {
        float* C = (float*)o.C;
#pragma unroll
        for (int i = 0; i < 4; ++i)
#pragma unroll
            for (int j = 0; j < 4; ++j)
#pragma unroll
                for (int r = 0; r < 4; ++r) {
                    int grow = row0 + wr + i * 16 + lq * 4 + r;
                    int gcol = col0 + wc + j * 16 + lm;
                    float v = acc[i][j][r];
                    long long ci = cb + (long long)grow * o.ldc + gcol;
                    if (o.flags & 2) v += o.add[ci];
                    C[ci] = v;
                }
    }
}

// ---------------------------------------------------------------------------
// 256x256 8-phase GEMM (m201 template geometry): BK=64, 512 threads (8 waves
// = 2Mx4N, per-wave output 128x64), 128KB double-buffered LDS. Per K-tile,
// 4 phases, each = { ds-read one quadrant's frags || stage 1 half-tile
// (2 gload16) -> barrier -> lgkmcnt(0) -> setprio(1) 16 MFMA setprio(0) ->
// barrier }. Staging schedule: P0/P1 stage A(t+1) into the OTHER buffer;
// P2/P3 stage B(t+2) into the CURRENT buffer's B region (dead after P1's
// barrier: all B reads of tile t complete there). Boundary wait = vmcnt(4)
// once per K-tile (leaves B(t+2)'s 4 loads in flight; never 0 mid-loop).
// T2 XOR swizzle via pre-swizzled global source + swizzled ds_read (verified:
// SQ_LDS_BANK_CONFLICT==0 in rounds 1-3).
// flags: 1=bf16 out, else fp32 out. Requires M%256==0, N%256==0, K%64==0.
__global__ __launch_bounds__(512) void gemm_256(GArgs ga) {
    __shared__ unsigned short LA[2][256 * 64];   // 2 x 32KB
    __shared__ unsigned short LB[2][256 * 64];   // 2 x 32KB

    int tid = blockIdx.x;
    int oi = 0;
    while (tid >= ga.op[oi].tileEnd) ++oi;
    GOp o = ga.op[oi];
    int local = tid - (oi ? ga.op[oi - 1].tileEnd : 0);
    int t = threadIdx.x;

    int perOp = o.gx * o.gy;
    int batch = local / perOp;
    int r3 = local - batch * perOp;
    int ty = r3 / o.gx, tx = r3 - ty * o.gx;
    int row0 = ty * 256, col0 = tx * 256;

    int zb = batch / o.nbh, zh = batch - zb * o.nbh;
    long long cb = (long long)zb * o.sCb + (long long)zh * o.sCh;

    const unsigned short* Ab = (const unsigned short*)o.A + zb * o.sAb + zh * o.sAh;
    const unsigned short* Bb = (const unsigned short*)o.B + zb * o.sBb + zh * o.sBh;

    int w = t >> 6, l = t & 63;
    // Stage addressing (verified r1): unit = 64 rows x 64 shorts (8KB), one
    // gload16/thread/unit. row-in-unit = w*8 + (l>>3); swizzled source col16
    // = (l&7)^(l>>3), LDS col-group = l&7. Coalescing preserved (perm within
    // 128B row segments).
    int srow = w * 8 + (l >> 3);
    int scol = ((l & 7) ^ (l >> 3)) << 3;   // shorts

    const unsigned short* aS0 = Ab + (long long)(row0 + srow) * o.lda + scol;
    const unsigned short* aS1 = Ab + (long long)(row0 + 64 + srow) * o.lda + scol;
    const unsigned short* aS2 = Ab + (long long)(row0 + 128 + srow) * o.lda + scol;
    const unsigned short* aS3 = Ab + (long long)(row0 + 192 + srow) * o.lda + scol;
    const unsigned short* bS0 = Bb + (long long)(col0 + srow) * o.ldb + scol;
    const unsigned short* bS1 = Bb + (long long)(col0 + 64 + srow) * o.ldb + scol;
    const unsigned short* bS2 = Bb + (long long)(col0 + 128 + srow) * o.ldb + scol;
    const unsigned short* bS3 = Bb + (long long)(col0 + 192 + srow) * o.ldb + scol;

    int wofs = w * 512;  // shorts; HW adds lane*16B

    int nkt = o.K >> 6;

    // prologue: B(0) -> LB[0], A(0) -> LA[0], B(1) -> LB[1]
    gload16(bS0, &LB[0][wofs]);
    gload16(bS1, &LB[0][4096 + wofs]);
    gload16(bS2, &LB[0][8192 + wofs]);
    gload16(bS3, &LB[0][12288 + wofs]);
    gload16(aS0, &LA[0][wofs]);
    gload16(aS1, &LA[0][4096 + wofs]);
    gload16(aS2, &LA[0][8192 + wofs]);
    gload16(aS3, &LA[0][12288 + wofs]);
    aS0 += 64; aS1 += 64; aS2 += 64; aS3 += 64;
    if (nkt > 1) {
        gload16(bS0 + 64, &LB[1][wofs]);
        gload16(bS1 + 64, &LB[1][4096 + wofs]);
        gload16(bS2 + 64, &LB[1][8192 + wofs]);
        gload16(bS3 + 64, &LB[1][12288 + wofs]);
    }
    bS0 += 128; bS1 += 128; bS2 += 128; bS3 += 128;
    if (nkt > 1) asm volatile("s_waitcnt vmcnt(4)" ::: "memory");
    else         asm volatile("s_waitcnt vmcnt(0)" ::: "memory");
    __builtin_amdgcn_s_barrier();
    __builtin_amdgcn_sched_barrier(0);

    int lm = l & 15, lq = l >> 4;
    int wr = w >> 2, wc = w & 3;      // 2x4 wave grid
    int c0 = ((lq) ^ (lm & 7)) << 3;
    int c1 = ((4 + lq) ^ (lm & 7)) << 3;

    f32x4 acc[8][4];
#pragma unroll
    for (int i = 0; i < 8; ++i)
#pragma unroll
        for (int j = 0; j < 4; ++j) acc[i][j] = (f32x4){0.f, 0.f, 0.f, 0.f};

    for (int kt = 0; kt < nkt; ++kt) {
        unsigned short* Ac = &LA[kt & 1][0];
        unsigned short* Bc = &LB[kt & 1][0];
        unsigned short* An = &LA[(kt & 1) ^ 1][0];
        bool pfA = (kt + 1 < nkt);
        bool pfB = (kt + 2 < nkt);

        short8 aR[4][2], bR0[2][2], bR1[2][2];

        // ---- P0: read A(m0-3)+B(n0-1); stage A-lo(t+1); MFMA Q00 ----
#pragma unroll
        for (int mi = 0; mi < 4; ++mi) {
            const unsigned short* ar = Ac + (wr * 128 + mi * 16 + lm) * 64;
            aR[mi][0] = *(const short8*)(ar + c0);
            aR[mi][1] = *(const short8*)(ar + c1);
        }
#pragma unroll
        for (int nj = 0; nj < 2; ++nj) {
            const unsigned short* br = Bc + (wc * 64 + nj * 16 + lm) * 64;
            bR0[nj][0] = *(const short8*)(br + c0);
            bR0[nj][1] = *(const short8*)(br + c1);
        }
        if (pfA) {
            gload16(aS0, An + wofs);
            gload16(aS1, An + 4096 + wofs);
        }
        __builtin_amdgcn_s_barrier();
        asm volatile("s_waitcnt lgkmcnt(0)" ::: "memory");
        __builtin_amdgcn_sched_barrier(0);
        __builtin_amdgcn_s_setprio(1);
#pragma unroll
        for (int kh = 0; kh < 2; ++kh)
#pragma unroll
            for (int mi = 0; mi < 4; ++mi)
#pragma unroll
                for (int nj = 0; nj < 2; ++nj)
                    acc[mi][nj] = __builtin_amdgcn_mfma_f32_16x16x32_bf16(aR[mi][kh], bR0[nj][kh], acc[mi][nj], 0, 0, 0);
        __builtin_amdgcn_s_setprio(0);
        __builtin_amdgcn_s_barrier();

        // ---- P1: read B(n2-3); stage A-hi(t+1); MFMA Q01 ----
#pragma unroll
        for (int nj = 0; nj < 2; ++nj) {
            const unsigned short* br = Bc + (wc * 64 + (nj + 2) * 16 + lm) * 64;
            bR1[nj][0] = *(const short8*)(br + c0);
            bR1[nj][1] = *(const short8*)(br + c1);
        }
        if (pfA) {
            gload16(aS2, An + 8192 + wofs);
            gload16(aS3, An + 12288 + wofs);
            aS0 += 64; aS1 += 64; aS2 += 64; aS3 += 64;
        }
        __builtin_amdgcn_s_barrier();
        asm volatile("s_waitcnt lgkmcnt(0)" ::: "memory");
        __builtin_amdgcn_sched_barrier(0);
        __builtin_amdgcn_s_setprio(1);
#pragma unroll
        for (int kh = 0; kh < 2; ++kh)
#pragma unroll
            for (int mi = 0; mi < 4; ++mi)
#pragma unroll
                for (int nj = 0; nj < 2; ++nj)
                    acc[mi][nj + 2] = __builtin_amdgcn_mfma_f32_16x16x32_bf16(aR[mi][kh], bR1[nj][kh], acc[mi][nj + 2], 0, 0, 0);
        __builtin_amdgcn_s_setprio(0);
        __builtin_amdgcn_s_barrier();

        // ---- P2: read A(m4-7) (reuse aR); stage B-lo(t+2) into CURRENT buf
        //      (B region dead: all tile-t B reads completed at P1's barrier);
        //      MFMA Q10 ----
#pragma unroll
        for (int mi = 0; mi < 4; ++mi) {
            const unsigned short* ar = Ac + (wr * 128 + (mi + 4) * 16 + lm) * 64;
            aR[mi][0] = *(const short8*)(ar + c0);
            aR[mi][1] = *(const short8*)(ar + c1);
        }
        if (pfB) {
            gload16(bS0, Bc + wofs);
            gload16(bS1, Bc + 4096 + wofs);
        }
        __builtin_amdgcn_s_barrier();
        asm volatile("s_waitcnt lgkmcnt(0)" ::: "memory");
        __builtin_amdgcn_sched_barrier(0);
        __builtin_amdgcn_s_setprio(1);
#pragma unroll
        for (int kh = 0; kh < 2; ++kh)
#pragma unroll
            for (int mi = 0; mi < 4; ++mi)
#pragma unroll
                for (int nj = 0; nj < 2; ++nj)
                    acc[mi + 4][nj] = __builtin_amdgcn_mfma_f32_16x16x32_bf16(aR[mi][kh], bR0[nj][kh], acc[mi + 4][nj], 0, 0, 0);
        __builtin_amdgcn_s_setprio(0);
        __builtin_amdgcn_s_barrier();

        // ---- P3: no reads; stage B-hi(t+2); MFMA Q11; boundary vmcnt ----
        if (pfB) {
            gload16(bS2, Bc + 8192 + wofs);
            gload16(bS3, Bc + 12288 + wofs);
            bS0 += 64; bS1 += 64; bS2 += 64; bS3 += 64;
        }
        __builtin_amdgcn_s_barrier();
        __builtin_amdgcn_sched_barrier(0);
        __builtin_amdgcn_s_setprio(1);
#pragma unroll
        for (int kh = 0; kh < 2; ++kh)
#pragma unroll
            for (int mi = 0; mi < 4; ++mi)
#pragma unroll
                for (int nj = 0; nj < 2; ++nj)
                    acc[mi + 4][nj + 2] = __builtin_amdgcn_mfma_f32_16x16x32_bf16(aR[mi][kh], bR1[nj][kh], acc[mi + 4][nj + 2], 0, 0, 0);
        __builtin_amdgcn_s_setprio(0);
        if (pfB) asm volatile("s_waitcnt vmcnt(4)" ::: "memory");
        else     asm volatile("s_waitcnt vmcnt(0)" ::: "memory");
        __builtin_amdgcn_sched_barrier(0);
        __builtin_amdgcn_s_barrier();
        __builtin_amdgcn_sched_barrier(0);
    }

    if (o.flags & 1) {
        __hip_bfloat16* C = (__hip_bfloat16*)o.C;
#pragma unroll
        for (int i = 0; i < 8; ++i)
#pragma unroll
            for (int j = 0; j < 4; ++j)
#pragma unroll
                for (int r = 0; r < 4; ++r) {
                    int grow = row0 + wr * 128 + i * 16 + lq * 4 + r;
                    int gcol = col0 + wc * 64 + j * 16 + lm;
                    C[cb + (long long)grow * o.ldc + gcol] = __float2bfloat16(acc[i][j][r]);
                }
    } else {
        float* C = (float*)o.C;
#pragma unroll
        for (int i = 0; i < 8; ++i)
#pragma unroll
            for (int j = 0; j < 4; ++j)
#pragma unroll
                for (int r = 0; r < 4; ++r) {
                    int grow = row0 + wr * 128 + i * 16 + lq * 4 + r;
                    int gcol = col0 + wc * 64 + j * 16 + lm;
                    C[cb + (long long)grow * o.ldc + gcol] = acc[i][j][r];
                }
    }
}

// ---------------------------------------------------------------------------
// rmsnorm (fp32 in, bf16 out), one block per row
__global__ __launch_bounds__(256) void rmsnorm_kernel(const float* __restrict__ x,
                                                      const float* __restrict__ w,
                                                      __hip_bfloat16* __restrict__ out) {
    long long base = (long long)blockIdx.x * Dz;
    int t = threadIdx.x;
    float v[8];
    float ss = 0.f;
#pragma unroll
    for (int p = 0; p < 8; ++p) { v[p] = x[base + t + p * 256]; ss += v[p] * v[p]; }
    __shared__ float red[256];
    red[t] = ss; __syncthreads();
    for (int s2 = 128; s2 > 0; s2 >>= 1) { if (t < s2) red[t] += red[t + s2]; __syncthreads(); }
    float sc = rsqrtf(red[0] / (float)Dz + 1e-6f);
#pragma unroll
    for (int p = 0; p < 8; ++p) { int c = t + p * 256; out[base + c] = __float2bfloat16(v[p] * sc * w[c]); }
}

// xmean phase 1: partial sums over 64-row chunks. grid = B*8sc*8dc = 256
__global__ __launch_bounds__(256) void xmean_p1(const __hip_bfloat16* __restrict__ xn,
                                                float* __restrict__ xmp) {
    int blk = blockIdx.x;
    int b = blk >> 6, sc = (blk >> 3) & 7, dc = blk & 7;
    int t = threadIdx.x;
    int d = dc * 256 + t;
    const __hip_bfloat16* p = xn + (long long)b * Sz * Dz + (long long)sc * 64 * Dz + d;
    float s = 0.f;
    for (int si = 0; si < 64; ++si) s += __bfloat162float(p[(long long)si * Dz]);
    xmp[(b * 8 + sc) * Dz + d] = s;
}

// mlp1 with integrated mean-reduction: h[b,j]=silu(xm@wc1+bc1). grid = B*16 = 64
__global__ __launch_bounds__(256) void mlp1_kernel(const float* __restrict__ xmp,
                                                   const float* __restrict__ wc1,
                                                   const float* __restrict__ bc1,
                                                   float* __restrict__ h) {
    int blk = blockIdx.x;
    int b = blk >> 4, jb = blk & 15;
    int t = threadIdx.x;
    __shared__ float xs[Dz];
    __shared__ float red[8][32];
    const float* P = xmp + b * 8 * Dz;
#pragma unroll
    for (int p = 0; p < 8; ++p) {
        int d = t + p * 256;
        float s = 0.f;
#pragma unroll
        for (int q = 0; q < 8; ++q) s += P[q * Dz + d];
        xs[d] = s * (1.0f / (float)Sz);
    }
    __syncthreads();
    int j = jb * 32 + (t & 31), ksl = t >> 5;
    float s = 0.f;
    for (int k = ksl * 256; k < ksl * 256 + 256; ++k)
        s += xs[k] * wc1[(long long)k * 512 + j];
    red[ksl][t & 31] = s;
    __syncthreads();
    if (t < 32) {
        float tot = 0.f;
#pragma unroll
        for (int q = 0; q < 8; ++q) tot += red[q][t];
        tot += bc1[jb * 32 + t];
        h[b * 512 + jb * 32 + t] = tot / (1.0f + expf(-tot));
    }
}

// coeffs with k-split. grid = B*128 = 512
__global__ __launch_bounds__(256) void coeffs_kernel(const float* __restrict__ h,
                                                     const float* __restrict__ wc2,
                                                     const float* __restrict__ bc2,
                                                     float* __restrict__ coeffs) {
    int blk = blockIdx.x;
    int b = blk >> 7, ib = blk & 127;
    int t = threadIdx.x;
    int i = ib * 64 + (t & 63), ksl = t >> 6;
    const float* hb = h + b * 512;
    float s = 0.f;
    for (int k = ksl * 128; k < ksl * 128 + 128; ++k)
        s += hb[k] * wc2[(long long)k * 8192 + i];
    __shared__ float red[4][64];
    red[ksl][t & 63] = s;
    __syncthreads();
    if (t < 64) {
        int ii = ib * 64 + t;
        float tot = red[0][t] + red[1][t] + red[2][t] + red[3][t] + bc2[ii];
        int kdeg = (ii >> 8) & 3;
        coeffs[b * 8192 + ii] = tot * (0.1f / (float)(kdeg + 1));
    }
}

// Chebyshev path; xn bf16 in, cheby/kv bf16 out
__global__ __launch_bounds__(256) void cheby_kernel(const __hip_bfloat16* __restrict__ xn,
                                                    const float* __restrict__ coeffs,
                                                    __hip_bfloat16* __restrict__ cheby_out,
                                                    __hip_bfloat16* __restrict__ kv_src) {
    int bs = blockIdx.x;
    int b = bs >> 9;
    long long base = (long long)bs * Dz;
    int t = threadIdx.x;
    __shared__ float xrow[Dz];
    __shared__ float hsum[NHz][33];
    __shared__ float T[NHz][4];
#pragma unroll
    for (int p = 0; p < 8; ++p) xrow[t + p * 256] = __bfloat162float(xn[base + t + p * 256]);
    __syncthreads();
    int hh = t >> 5, lane = t & 31;
    float s = 0.f;
#pragma unroll
    for (int q = 0; q < 8; ++q) s += xrow[hh * HDz + lane + q * 32];
    hsum[hh][lane] = s;
    __syncthreads();
    if (t < NHz) {
        float tot = 0.f;
        for (int l2 = 0; l2 < 32; ++l2) tot += hsum[t][l2];
        float z = tanhf(tot / (float)HDz);
        float t2 = 2.f * z * z - 1.f;
        T[t][0] = 1.f; T[t][1] = z; T[t][2] = t2; T[t][3] = 2.f * z * t2 - z;
    }
    __syncthreads();
    const float* cbp = coeffs + (long long)b * (NHz * DEGz * HDz);
#pragma unroll
    for (int p = 0; p < 8; ++p) {
        int e = t + p * 256;
        int hd = e >> 8;
        int d = e & (HDz - 1);
        const float* ch = cbp + hd * (DEGz * HDz) + d;
        float co = T[hd][0] * ch[0] + T[hd][1] * ch[HDz] + T[hd][2] * ch[2 * HDz] + T[hd][3] * ch[3 * HDz];
        cheby_out[base + e] = __float2bfloat16(co);
        kv_src[base + e] = __float2bfloat16(xrow[e] + co);
    }
}

// softmax over 512-wide bf16 rows; applies causal mask itself
__global__ __launch_bounds__(128) void softmax_kernel(__hip_bfloat16* __restrict__ sc) {
    long long rid = blockIdx.x;
    int i = (int)(rid & (Sz - 1));
    long long base = rid * Sz;
    int t = threadIdx.x;
    float vals[4];
    float mx = -1e30f;
#pragma unroll
    for (int p = 0; p < 4; ++p) {
        int j = t + p * 128;
        float v = __bfloat162float(sc[base + j]);
        if (j > i) v = -1e9f;
        vals[p] = v;
        mx = fmaxf(mx, v);
    }
    __shared__ float red[128];
    red[t] = mx; __syncthreads();
    for (int s2 = 64; s2 > 0; s2 >>= 1) { if (t < s2) red[t] = fmaxf(red[t], red[t + s2]); __syncthreads(); }
    mx = red[0]; __syncthreads();
    float sum = 0.f;
#pragma unroll
    for (int p = 0; p < 4; ++p) { vals[p] = __expf(vals[p] - mx); sum += vals[p]; }
    red[t] = sum; __syncthreads();
    for (int s2 = 64; s2 > 0; s2 >>= 1) { if (t < s2) red[t] += red[t + s2]; __syncthreads(); }
    float inv = 1.0f / red[0];
#pragma unroll
    for (int p = 0; p < 4; ++p) sc[base + t + p * 128] = __float2bfloat16(vals[p] * inv);
}

// hcat = [rmsnorm(cheby,w_nc), rmsnorm(slr,w_ns)]
__global__ __launch_bounds__(256) void hcat_kernel(const __hip_bfloat16* __restrict__ cheby,
                                                   const __hip_bfloat16* __restrict__ slr,
                                                   const float* __restrict__ w_nc,
                                                   const float* __restrict__ w_ns,
                                                   __hip_bfloat16* __restrict__ hcat) {
    long long row = blockIdx.x;
    const __hip_bfloat16* c = cheby + row * Dz;
    const __hip_bfloat16* sl = slr + row * Dz;
    __hip_bfloat16* o = hcat + row * (2 * Dz);
    int t = threadIdx.x;
    float v1[8], v2[8];
    float ss1 = 0.f, ss2 = 0.f;
#pragma unroll
    for (int p = 0; p < 8; ++p) {
        v1[p] = __bfloat162float(c[t + p * 256]);  ss1 += v1[p] * v1[p];
        v2[p] = __bfloat162float(sl[t + p * 256]); ss2 += v2[p] * v2[p];
    }
    __shared__ float red[256];
    red[t] = ss1; __syncthreads();
    for (int s2 = 128; s2 > 0; s2 >>= 1) { if (t < s2) red[t] += red[t + s2]; __syncthreads(); }
    float sc1 = rsqrtf(red[0] / (float)Dz + 1e-6f);
    __syncthreads();
    red[t] = ss2; __syncthreads();
    for (int s2 = 128; s2 > 0; s2 >>= 1) { if (t < s2) red[t] += red[t + s2]; __syncthreads(); }
    float sc2 = rsqrtf(red[0] / (float)Dz + 1e-6f);
#pragma unroll
    for (int p = 0; p < 8; ++p) {
        int cx = t + p * 256;
        o[cx] = __float2bfloat16(v1[p] * sc1 * w_nc[cx]);
        o[Dz + cx] = __float2bfloat16(v2[p] * sc2 * w_ns[cx]);
    }
}

// fused = rmsnorm(silu(gate)*value, w_np) — gate/value are each the sum of two
// fp32 split-K partials (the gv GEMM's K-reduction folds in here)
__global__ __launch_bounds__(256) void fusedgate2_kernel(const float* __restrict__ p0g,
                                                         const float* __restrict__ p0v,
                                                         const float* __restrict__ p1g,
                                                         const float* __restrict__ p1v,
                                                         const float* __restrict__ w_np,
                                                         __hip_bfloat16* __restrict__ fused) {
    long long row = blockIdx.x;
    long long rb = row * Dz;
    __hip_bfloat16* o = fused + row * Dz;
    int t = threadIdx.x;
    float f[8];
    float ss = 0.f;
#pragma unroll
    for (int p = 0; p < 8; ++p) {
        int cx = t + p * 256;
        float ga = p0g[rb + cx] + p1g[rb + cx];
        float va = p0v[rb + cx] + p1v[rb + cx];
        float sv = ga / (1.0f + expf(-ga)) * va;
        f[p] = sv; ss += sv * sv;
    }
    __shared__ float red[256];
    red[t] = ss; __syncthreads();
    for (int s2 = 128; s2 > 0; s2 >>= 1) { if (t < s2) red[t] += red[t + s2]; __syncthreads(); }
    float sc = rsqrtf(red[0] / (float)Dz + 1e-6f);
#pragma unroll
    for (int p = 0; p < 8; ++p) { int cx = t + p * 256; o[cx] = __float2bfloat16(f[p] * sc * w_np[cx]); }
}

// ---------------------------------------------------------------------------
static GOp gop(const void* A, const void* B, void* C, const float* add,
               int K, int lda, int ldb, int ldc, int nbh, int nb, int gx, int gy,
               long long sAb, long long sAh, long long sBb, long long sBh,
               long long sCb, long long sCh, int flags) {
    GOp o;
    o.A = A; o.B = B; o.C = C; o.add = add;
    o.sAb = sAb; o.sAh = sAh; o.sBb = sBb; o.sBh = sBh; o.sCb = sCb; o.sCh = sCh;
    o.K = K; o.lda = lda; o.ldb = ldb; o.ldc = ldc; o.nbh = nbh;
    o.gx = gx; o.gy = gy; o.flags = flags;
    o.tileEnd = (flags & 32) ? gx * gy : nb * gx * gy;  // count; prefixed later
    return o;
}

static void launch_multi(hipStream_t st, GOp* ops, int n) {
    GArgs ga; ga.n = n;
    int acc = 0;
    for (int i = 0; i < n; ++i) { acc += ops[i].tileEnd; ga.op[i] = ops[i]; ga.op[i].tileEnd = acc; }
    hipLaunchKernelGGL(gemm_multi, dim3(acc), dim3(256), 0, st, ga);
}

static void launch_256(hipStream_t st, GOp* ops, int n) {
    GArgs ga; ga.n = n;
    int acc = 0;
    for (int i = 0; i < n; ++i) { acc += ops[i].tileEnd; ga.op[i] = ops[i]; ga.op[i].tileEnd = acc; }
    hipLaunchKernelGGL(gemm_256, dim3(acc), dim3(512), 0, st, ga);
}

extern "C" void kernel_launch(void* const* d_in, const int* in_sizes, int n_in,
                              void* d_out, int out_size, void* d_ws, size_t ws_size,
                              hipStream_t stream) {
    const float* x     = (const float*)d_in[0];
    const float* w_in  = (const float*)d_in[1];
    const float* wc1   = (const float*)d_in[6];
    const float* bc1   = (const float*)d_in[7];
    const float* wc2   = (const float*)d_in[8];
    const float* bc2   = (const float*)d_in[9];
    const float* wq    = (const float*)d_in[10];
    const float* wk    = (const float*)d_in[11];
    const float* wv    = (const float*)d_in[12];
    const float* wo    = (const float*)d_in[13];
    const float* w_nc  = (const float*)d_in[14];
    const float* w_ns  = (const float*)d_in[15];
    const float* w_fgv = (const float*)d_in[16];
    const float* w_np  = (const float*)d_in[17];
    const float* w_out = (const float*)d_in[18];
    float* out = (float*)d_out;

    const size_t MB = 1ull << 20;
    char* W = (char*)d_ws;
    __hip_bfloat16* xn_bf    = (__hip_bfloat16*)(W + 0 * MB);
    __hip_bfloat16* kv_bf    = (__hip_bfloat16*)(W + 8 * MB);
    __hip_bfloat16* cheby_bf = (__hip_bfloat16*)(W + 16 * MB);
    __hip_bfloat16* q_bf     = (__hip_bfloat16*)(W + 24 * MB);
    __hip_bfloat16* k_bf     = (__hip_bfloat16*)(W + 32 * MB);
    __hip_bfloat16* vT_bf    = (__hip_bfloat16*)(W + 40 * MB);
    __hip_bfloat16* o_bf     = (__hip_bfloat16*)(W + 48 * MB);
    __hip_bfloat16* scores   = (__hip_bfloat16*)(W + 56 * MB);   // 32MB
    __hip_bfloat16* wq_t     = (__hip_bfloat16*)(W + 88 * MB);
    __hip_bfloat16* wk_t     = (__hip_bfloat16*)(W + 96 * MB);
    __hip_bfloat16* wv_t     = (__hip_bfloat16*)(W + 104 * MB);
    __hip_bfloat16* wo_t     = (__hip_bfloat16*)(W + 112 * MB);
    __hip_bfloat16* wout_t   = (__hip_bfloat16*)(W + 120 * MB);
    // lifetime reuse (scores region becomes wfgv_t only AFTER PV has consumed it)
    __hip_bfloat16* wfgv_t   = (__hip_bfloat16*)(W + 56 * MB);
    __hip_bfloat16* slr_bf   = (__hip_bfloat16*)(W + 0 * MB);    // xn dead
    __hip_bfloat16* hcat_bf  = (__hip_bfloat16*)(W + 24 * MB);   // q,k dead (16MB)
    __hip_bfloat16* fused_bf = (__hip_bfloat16*)(W + 16 * MB);   // cheby dead after L12
    // gv split-K fp32 partials (16MB each), in regions dead at L13:
    float* p0g = (float*)(W + 0 * MB);    // slr dead after L12
    float* p0v = (float*)(W + 40 * MB);   // vT dead after L10, o dead after L11
    float* p1g = (float*)(W + 88 * MB);   // wq_t dead after L8
    float* p1v = (float*)(W + 104 * MB);  // wv_t dead after L7, wo_t dead after L11
    float* xmp   = (float*)(W + 128 * MB);                       // 8*B*D
    float* hbuf  = xmp + 65536;
    float* cbuf  = hbuf + 2048;

    const int BS = Bz * Sz;
    const long long SD = (long long)Sz * Dz;
    const long long SS = (long long)Sz * Sz;

    // L1: five 2048x2048 weight transposes in one launch
    {
        GOp ops[5];
        const float* srcs[5] = {wq, wk, wv, wo, w_out};
        __hip_bfloat16* dsts[5] = {wq_t, wk_t, wv_t, wo_t, wout_t};
        for (int i = 0; i < 5; ++i)
            ops[i] = gop(srcs[i], nullptr, dsts[i], nullptr, Dz, Dz, 0, Dz,
                         1, 1, 64, 64, 0, 0, 0, 0, 0, 0, 32);
        launch_multi(stream, ops, 5);
    }
    // L2: xn = rmsnorm(x)
    hipLaunchKernelGGL(rmsnorm_kernel, dim3(BS), dim3(256), 0, stream, x, w_in, xn_bf);
    // L3-L5: coeff path
    hipLaunchKernelGGL(xmean_p1, dim3(256), dim3(256), 0, stream, xn_bf, xmp);
    hipLaunchKernelGGL(mlp1_kernel, dim3(64), dim3(256), 0, stream, xmp, wc1, bc1, hbuf);
    hipLaunchKernelGGL(coeffs_kernel, dim3(512), dim3(256), 0, stream, hbuf, wc2, bc2, cbuf);
    // L6: cheby + kv_src
    hipLaunchKernelGGL(cheby_kernel, dim3(BS), dim3(256), 0, stream, xn_bf, cbuf, cheby_bf, kv_bf);
    // L7: q, k, vT via 256^2 8-phase GEMM (64+64+64 = 192 blocks)
    {
        GOp ops[3];
        ops[0] = gop(xn_bf, wq_t, q_bf, nullptr, Dz, Dz, Dz, Dz, 1, 1, 8, 8,
                     0, 0, 0, 0, 0, 0, 1);
        ops[1] = gop(kv_bf, wk_t, k_bf, nullptr, Dz, Dz, Dz, Dz, 1, 1, 8, 8,
                     0, 0, 0, 0, 0, 0, 1);
        ops[2] = gop(wv_t, kv_bf, vT_bf, nullptr, Dz, Dz, Dz, Sz, 1, Bz, 2, 8,
                     0, 0, SD, 0, (long long)Dz * Sz, 0, 1);
        launch_256(stream, ops, 3);
    }
    // L8: scores = q@k^T, scale+mask epilogue, skip masked tiles (legacy kernel)
    {
        GOp op = gop(q_bf, k_bf, scores, nullptr, AHDz, Dz, Dz, Sz, AHz, Bz * AHz, 4, 4,
                     SD, AHDz, SD, AHDz, (long long)AHz * SS, SS, 1 | 4);
        launch_multi(stream, &op, 1);
    }
    // L9: softmax (applies causal mask)
    hipLaunchKernelGGL(softmax_kernel, dim3(Bz * AHz * Sz), dim3(128), 0, stream, scores);
    // L10: PV alone (reads scores — nothing may write the scores region here!)
    {
        GOp op = gop(scores, vT_bf, o_bf, nullptr, Sz, Sz, Sz, Dz, AHz, Bz * AHz, 1, 4,
                     (long long)AHz * SS, SS, (long long)Dz * Sz, 128LL * Sz,
                     SD, 128, 1 | 8);
        launch_multi(stream, &op, 1);
    }
    // L11: slr = o @ wo (legacy, full-chip 256 blocks) + wfgv transpose in ONE
    // launch so the memory-bound transpose overlaps the compute-bound GEMM
    {
        GOp ops[2];
        ops[0] = gop(o_bf, wo_t, slr_bf, nullptr, Dz, Dz, Dz, Dz, 1, 1, 16, 16,
                     0, 0, 0, 0, 0, 0, 1);
        ops[1] = gop(w_fgv, nullptr, wfgv_t, nullptr, 2 * Dz, 2 * Dz, 0, 2 * Dz,
                     1, 1, 128, 128, 0, 0, 0, 0, 0, 0, 32);
        launch_multi(stream, ops, 2);
    }
    // L12: hcat
    hipLaunchKernelGGL(hcat_kernel, dim3(BS), dim3(256), 0, stream, cheby_bf, slr_bf, w_nc, w_ns, hcat_bf);
    // L13: gv = hcat @ w_fgv via 256^2 GEMM, split 4 ways (K-half x gate/value
    // N-half) = 4 x 64 = 256 blocks (exact chip fill); fp32 partials, the
    // K-reduction folds into fusedgate2.
    {
        const unsigned short* hc = (const unsigned short*)hcat_bf;
        const unsigned short* wf = (const unsigned short*)wfgv_t;
        GOp ops[4];
        ops[0] = gop(hc,        wf,                      p0g, nullptr, Dz, 2 * Dz, 2 * Dz, Dz,
                     1, 1, 8, 8, 0, 0, 0, 0, 0, 0, 0);
        ops[1] = gop(hc,        wf + 2048LL * 4096,      p0v, nullptr, Dz, 2 * Dz, 2 * Dz, Dz,
                     1, 1, 8, 8, 0, 0, 0, 0, 0, 0, 0);
        ops[2] = gop(hc + 2048, wf + 2048,               p1g, nullptr, Dz, 2 * Dz, 2 * Dz, Dz,
                     1, 1, 8, 8, 0, 0, 0, 0, 0, 0, 0);
        ops[3] = gop(hc + 2048, wf + 2048LL * 4096 + 2048, p1v, nullptr, Dz, 2 * Dz, 2 * Dz, Dz,
                     1, 1, 8, 8, 0, 0, 0, 0, 0, 0, 0);
        launch_256(stream, ops, 4);
    }
    // L14: fused gate (+ gv K-reduction)
    hipLaunchKernelGGL(fusedgate2_kernel, dim3(BS), dim3(256), 0, stream,
                       p0g, p0v, p1g, p1v, w_np, fused_bf);
    // L15: out = x + fused @ w_out (legacy, full-chip 256 blocks)
    {
        GOp op = gop(fused_bf, wout_t, out, x, Dz, Dz, Dz, Dz, 1, 1, 16, 16,
                     0, 0, 0, 0, 0, 0, 2);
        launch_multi(stream, &op, 1);
    }
}

// Round 5
// 575.788 us; speedup vs baseline: 1.1076x; 1.0169x over previous
//
#include <hip/hip_runtime.h>
#include <hip/hip_bf16.h>
#include <math.h>

#define Bz 4
#define Sz 512
#define Dz 2048
#define NHz 8
#define DEGz 4
#define HDz 256
#define AHz 16
#define AHDz 128
#define SCALE_ATT 0.08838834764831845f  // 1/sqrt(128)

typedef __attribute__((ext_vector_type(8))) short short8;
typedef __attribute__((ext_vector_type(4))) float f32x4;

#define AS1 __attribute__((address_space(1)))
#define AS3 __attribute__((address_space(3)))

__device__ inline void gload16(const void* g, void* l) {
    __builtin_amdgcn_global_load_lds((const AS1 void*)g, (AS3 void*)l, 16, 0, 0);
}

// ---------------------------------------------------------------------------
// Multi-op GEMM/transpose dispatcher (legacy 128x128 structure).
// GEMM op: C[m][n] = sum_k A[m][k]*BT[n][k].
// flags: 1=bf16 out, 2=fp32 residual add, 4=score epilogue (scale+causal,
//        skip fully-masked tiles), 8=causal K-limit (kEnd=row0+128),
//        32=transpose+cvt op (A=fp32 src, C=bf16 dst)
struct GOp {
    const void* A; const void* B; void* C; const float* add;
    long long sAb, sAh, sBb, sBh, sCb, sCh;
    int K, lda, ldb, ldc, nbh, gx, gy, flags, tileEnd;
};
struct GArgs { int n; GOp op[6]; };

__global__ __launch_bounds__(256) void gemm_multi(GArgs ga) {
    __shared__ unsigned short As[2 * 128 * 32];
    __shared__ unsigned short Bs[2 * 128 * 32];

    int tid = blockIdx.x;
    int oi = 0;
    while (tid >= ga.op[oi].tileEnd) ++oi;
    GOp o = ga.op[oi];
    int local = tid - (oi ? ga.op[oi - 1].tileEnd : 0);
    int t = threadIdx.x;

    if (o.flags & 32) {
        // 32x32 transpose + fp32->bf16
        const float* src = (const float*)o.A;
        __hip_bfloat16* dst = (__hip_bfloat16*)o.C;
        int ty = local / o.gx, tx = local - ty * o.gx;
        int k0 = ty * 32, n0 = tx * 32;
        float* tile = (float*)As;  // [32][33]
        int c = t & 31, r8 = t >> 5;
#pragma unroll
        for (int p = 0; p < 4; ++p)
            tile[(r8 + p * 8) * 33 + c] = src[(long long)(k0 + r8 + p * 8) * o.lda + n0 + c];
        __syncthreads();
#pragma unroll
        for (int p = 0; p < 4; ++p)
            dst[(long long)(n0 + r8 + p * 8) * o.ldc + k0 + c] =
                __float2bfloat16(tile[c * 33 + r8 + p * 8]);
        return;
    }

    int perOp = o.gx * o.gy;
    int batch = local / perOp;
    int r3 = local - batch * perOp;
    int ty = r3 / o.gx;
    int tx = r3 - ty * o.gx;
    int row0 = ty * 128, col0 = tx * 128;

    if ((o.flags & 4) && (col0 > row0 + 127)) return;  // fully masked: softmax masks

    int zb = batch / o.nbh, zh = batch - zb * o.nbh;
    long long cb = (long long)zb * o.sCb + (long long)zh * o.sCh;

    int kEnd = o.K;
    if (o.flags & 8) { int ke = row0 + 128; kEnd = kEnd < ke ? kEnd : ke; }

    const unsigned short* Ab = (const unsigned short*)o.A + zb * o.sAb + zh * o.sAh;
    const unsigned short* Bb = (const unsigned short*)o.B + zb * o.sBb + zh * o.sBh;

    int w = t >> 6, l = t & 63;
    int lrow = l >> 2;
    int lchunk = (l & 3) * 8;

    const unsigned short* aP0 = Ab + (long long)(row0 + w * 16 + lrow) * o.lda + lchunk;
    const unsigned short* aP1 = aP0 + 64LL * o.lda;
    const unsigned short* bP0 = Bb + (long long)(col0 + w * 16 + lrow) * o.ldb + lchunk;
    const unsigned short* bP1 = bP0 + 64LL * o.ldb;
    unsigned short* aL0 = As + w * 512;
    unsigned short* aL1 = As + (w + 4) * 512;
    unsigned short* bL0 = Bs + w * 512;
    unsigned short* bL1 = Bs + (w + 4) * 512;

    int lm = l & 15, lq = l >> 4;
    int wr = (w >> 1) * 64, wc = (w & 1) * 64;

    f32x4 acc[4][4];
#pragma unroll
    for (int i = 0; i < 4; ++i)
#pragma unroll
        for (int j = 0; j < 4; ++j) acc[i][j] = (f32x4){0.f, 0.f, 0.f, 0.f};

    for (int k0 = 0; k0 < kEnd; k0 += 64) {
        gload16(aP0, aL0);
        gload16(aP1, aL1);
        gload16(bP0, bL0);
        gload16(bP1, bL1);
        gload16(aP0 + 32, aL0 + 4096);
        gload16(aP1 + 32, aL1 + 4096);
        gload16(bP0 + 32, bL0 + 4096);
        gload16(bP1 + 32, bL1 + 4096);
        aP0 += 64; aP1 += 64; bP0 += 64; bP1 += 64;
        __syncthreads();

#pragma unroll
        for (int h = 0; h < 2; ++h) {
            const unsigned short* Ah = As + h * 4096;
            const unsigned short* Bh = Bs + h * 4096;
            short8 af[4], bfr[4];
#pragma unroll
            for (int i = 0; i < 4; ++i)
                af[i] = *(const short8*)(Ah + (wr + i * 16 + lm) * 32 + lq * 8);
#pragma unroll
            for (int j = 0; j < 4; ++j)
                bfr[j] = *(const short8*)(Bh + (wc + j * 16 + lm) * 32 + lq * 8);
#pragma unroll
            for (int i = 0; i < 4; ++i)
#pragma unroll
                for (int j = 0; j < 4; ++j)
                    acc[i][j] = __builtin_amdgcn_mfma_f32_16x16x32_bf16(af[i], bfr[j], acc[i][j], 0, 0, 0);
        }
        __syncthreads();
    }

    if (o.flags & 1) {
        __hip_bfloat16* C = (__hip_bfloat16*)o.C;
#pragma unroll
        for (int i = 0; i < 4; ++i)
#pragma unroll
            for (int j = 0; j < 4; ++j)
#pragma unroll
                for (int r = 0; r < 4; ++r) {
                    int grow = row0 + wr + i * 16 + lq * 4 + r;
                    int gcol = col0 + wc + j * 16 + lm;
                    float v = acc[i][j][r];
                    if (o.flags & 4) v = (gcol > grow) ? -1e9f : v * SCALE_ATT;
                    C[cb + (long long)grow * o.ldc + gcol] = __float2bfloat16(v);
                }
    } else {
        float* C = (float*)o.C;
#pragma unroll
        for (int i = 0; i < 4; ++i)
#pragma unroll
            for (int j = 0; j < 4; ++j)
#pragma unroll
                for (int r = 0; r < 4; ++r) {
                    int grow = row0 + wr + i * 16 + lq * 4 + r;
                    int gcol = col0 + wc + j * 16 + lm;
                    float v = acc[i][j][r];
                    long long ci = cb + (long long)grow * o.ldc + gcol;
                    if (o.flags & 2) v += o.add[ci];
                    C[ci] = v;
                }
    }
}

// ---------------------------------------------------------------------------
// 256x256 8-phase GEMM (m201 geometry): BK=64, 512 threads (8 waves = 2Mx4N,
// per-wave output 128x64), 128KB double-buffered LDS. Per K-tile, 4 phases:
//   { ds-read quadrant frags || stage (2 gload16) -> lgkmcnt(0) (own reads)
//     -> sched_barrier -> setprio(1) 16 MFMA setprio(0) -> s_barrier }.
// NO barrier before the MFMA cluster (round-5 change): each wave gates its
// MFMA only on its OWN lgkmcnt, so waves skew within a phase and the LDS-read
// pipe overlaps the MFMA pipe across waves. The end-of-phase barrier (with
// reads already drained per-wave) preserves the two hard invariants:
//  (a) P2 stages B(t+2) into CURRENT buf B only after end-P1 barrier, by which
//      every wave drained its B reads (its P1 lgkmcnt(0));
//  (b) buffer swap at end-P3 with vmcnt(4): A(t+1),B(t+1) complete, B(t+2)'s
//      4 loads stay in flight (counted, never 0 mid-loop).
// sched_barrier(0) after every s_barrier pins memory ops inside their phase.
// T2 XOR swizzle via pre-swizzled global source + swizzled ds_read (verified:
// SQ_LDS_BANK_CONFLICT==0 rounds 1-4).
// flags: 1=bf16 out, else fp32 out. Requires M%256==0, N%256==0, K%64==0.
__global__ __launch_bounds__(512) void gemm_256(GArgs ga) {
    __shared__ unsigned short LA[2][256 * 64];   // 2 x 32KB
    __shared__ unsigned short LB[2][256 * 64];   // 2 x 32KB

    int tid = blockIdx.x;
    int oi = 0;
    while (tid >= ga.op[oi].tileEnd) ++oi;
    GOp o = ga.op[oi];
    int local = tid - (oi ? ga.op[oi - 1].tileEnd : 0);
    int t = threadIdx.x;

    int perOp = o.gx * o.gy;
    int batch = local / perOp;
    int r3 = local - batch * perOp;
    int ty = r3 / o.gx, tx = r3 - ty * o.gx;
    int row0 = ty * 256, col0 = tx * 256;

    int zb = batch / o.nbh, zh = batch - zb * o.nbh;
    long long cb = (long long)zb * o.sCb + (long long)zh * o.sCh;

    const unsigned short* Ab = (const unsigned short*)o.A + zb * o.sAb + zh * o.sAh;
    const unsigned short* Bb = (const unsigned short*)o.B + zb * o.sBb + zh * o.sBh;

    int w = t >> 6, l = t & 63;
    // Stage addressing (verified r1): unit = 64 rows x 64 shorts (8KB), one
    // gload16/thread/unit. row-in-unit = w*8 + (l>>3); swizzled source col16
    // = (l&7)^(l>>3), LDS col-group = l&7. Coalescing preserved (perm within
    // 128B row segments).
    int srow = w * 8 + (l >> 3);
    int scol = ((l & 7) ^ (l >> 3)) << 3;   // shorts

    const unsigned short* aS0 = Ab + (long long)(row0 + srow) * o.lda + scol;
    const unsigned short* aS1 = Ab + (long long)(row0 + 64 + srow) * o.lda + scol;
    const unsigned short* aS2 = Ab + (long long)(row0 + 128 + srow) * o.lda + scol;
    const unsigned short* aS3 = Ab + (long long)(row0 + 192 + srow) * o.lda + scol;
    const unsigned short* bS0 = Bb + (long long)(col0 + srow) * o.ldb + scol;
    const unsigned short* bS1 = Bb + (long long)(col0 + 64 + srow) * o.ldb + scol;
    const unsigned short* bS2 = Bb + (long long)(col0 + 128 + srow) * o.ldb + scol;
    const unsigned short* bS3 = Bb + (long long)(col0 + 192 + srow) * o.ldb + scol;

    int wofs = w * 512;  // shorts; HW adds lane*16B

    int nkt = o.K >> 6;

    // prologue: B(0) -> LB[0], A(0) -> LA[0], B(1) -> LB[1]
    gload16(bS0, &LB[0][wofs]);
    gload16(bS1, &LB[0][4096 + wofs]);
    gload16(bS2, &LB[0][8192 + wofs]);
    gload16(bS3, &LB[0][12288 + wofs]);
    gload16(aS0, &LA[0][wofs]);
    gload16(aS1, &LA[0][4096 + wofs]);
    gload16(aS2, &LA[0][8192 + wofs]);
    gload16(aS3, &LA[0][12288 + wofs]);
    aS0 += 64; aS1 += 64; aS2 += 64; aS3 += 64;
    if (nkt > 1) {
        gload16(bS0 + 64, &LB[1][wofs]);
        gload16(bS1 + 64, &LB[1][4096 + wofs]);
        gload16(bS2 + 64, &LB[1][8192 + wofs]);
        gload16(bS3 + 64, &LB[1][12288 + wofs]);
    }
    bS0 += 128; bS1 += 128; bS2 += 128; bS3 += 128;
    if (nkt > 1) asm volatile("s_waitcnt vmcnt(4)" ::: "memory");
    else         asm volatile("s_waitcnt vmcnt(0)" ::: "memory");
    __builtin_amdgcn_s_barrier();
    __builtin_amdgcn_sched_barrier(0);

    int lm = l & 15, lq = l >> 4;
    int wr = w >> 2, wc = w & 3;      // 2x4 wave grid
    int c0 = ((lq) ^ (lm & 7)) << 3;
    int c1 = ((4 + lq) ^ (lm & 7)) << 3;

    f32x4 acc[8][4];
#pragma unroll
    for (int i = 0; i < 8; ++i)
#pragma unroll
        for (int j = 0; j < 4; ++j) acc[i][j] = (f32x4){0.f, 0.f, 0.f, 0.f};

    for (int kt = 0; kt < nkt; ++kt) {
        unsigned short* Ac = &LA[kt & 1][0];
        unsigned short* Bc = &LB[kt & 1][0];
        unsigned short* An = &LA[(kt & 1) ^ 1][0];
        bool pfA = (kt + 1 < nkt);
        bool pfB = (kt + 2 < nkt);

        short8 aR[4][2], bR0[2][2], bR1[2][2];

        // ---- P0: read A(m0-3)+B(n0-1); stage A-lo(t+1); MFMA Q00 ----
#pragma unroll
        for (int mi = 0; mi < 4; ++mi) {
            const unsigned short* ar = Ac + (wr * 128 + mi * 16 + lm) * 64;
            aR[mi][0] = *(const short8*)(ar + c0);
            aR[mi][1] = *(const short8*)(ar + c1);
        }
#pragma unroll
        for (int nj = 0; nj < 2; ++nj) {
            const unsigned short* br = Bc + (wc * 64 + nj * 16 + lm) * 64;
            bR0[nj][0] = *(const short8*)(br + c0);
            bR0[nj][1] = *(const short8*)(br + c1);
        }
        if (pfA) {
            gload16(aS0, An + wofs);
            gload16(aS1, An + 4096 + wofs);
        }
        asm volatile("s_waitcnt lgkmcnt(0)" ::: "memory");
        __builtin_amdgcn_sched_barrier(0);
        __builtin_amdgcn_s_setprio(1);
#pragma unroll
        for (int kh = 0; kh < 2; ++kh)
#pragma unroll
            for (int mi = 0; mi < 4; ++mi)
#pragma unroll
                for (int nj = 0; nj < 2; ++nj)
                    acc[mi][nj] = __builtin_amdgcn_mfma_f32_16x16x32_bf16(aR[mi][kh], bR0[nj][kh], acc[mi][nj], 0, 0, 0);
        __builtin_amdgcn_s_setprio(0);
        __builtin_amdgcn_s_barrier();
        __builtin_amdgcn_sched_barrier(0);

        // ---- P1: read B(n2-3); stage A-hi(t+1); MFMA Q01 ----
#pragma unroll
        for (int nj = 0; nj < 2; ++nj) {
            const unsigned short* br = Bc + (wc * 64 + (nj + 2) * 16 + lm) * 64;
            bR1[nj][0] = *(const short8*)(br + c0);
            bR1[nj][1] = *(const short8*)(br + c1);
        }
        if (pfA) {
            gload16(aS2, An + 8192 + wofs);
            gload16(aS3, An + 12288 + wofs);
            aS0 += 64; aS1 += 64; aS2 += 64; aS3 += 64;
        }
        asm volatile("s_waitcnt lgkmcnt(0)" ::: "memory");
        __builtin_amdgcn_sched_barrier(0);
        __builtin_amdgcn_s_setprio(1);
#pragma unroll
        for (int kh = 0; kh < 2; ++kh)
#pragma unroll
            for (int mi = 0; mi < 4; ++mi)
#pragma unroll
                for (int nj = 0; nj < 2; ++nj)
                    acc[mi][nj + 2] = __builtin_amdgcn_mfma_f32_16x16x32_bf16(aR[mi][kh], bR1[nj][kh], acc[mi][nj + 2], 0, 0, 0);
        __builtin_amdgcn_s_setprio(0);
        __builtin_amdgcn_s_barrier();   // B reads of tile t drained by all waves
        __builtin_amdgcn_sched_barrier(0);

        // ---- P2: read A(m4-7) (reuse aR); stage B-lo(t+2) into CURRENT buf
        //      (B region dead after end-P1 barrier); MFMA Q10 ----
#pragma unroll
        for (int mi = 0; mi < 4; ++mi) {
            const unsigned short* ar = Ac + (wr * 128 + (mi + 4) * 16 + lm) * 64;
            aR[mi][0] = *(const short8*)(ar + c0);
            aR[mi][1] = *(const short8*)(ar + c1);
        }
        if (pfB) {
            gload16(bS0, Bc + wofs);
            gload16(bS1, Bc + 4096 + wofs);
        }
        asm volatile("s_waitcnt lgkmcnt(0)" ::: "memory");
        __builtin_amdgcn_sched_barrier(0);
        __builtin_amdgcn_s_setprio(1);
#pragma unroll
        for (int kh = 0; kh < 2; ++kh)
#pragma unroll
            for (int mi = 0; mi < 4; ++mi)
#pragma unroll
                for (int nj = 0; nj < 2; ++nj)
                    acc[mi + 4][nj] = __builtin_amdgcn_mfma_f32_16x16x32_bf16(aR[mi][kh], bR0[nj][kh], acc[mi + 4][nj], 0, 0, 0);
        __builtin_amdgcn_s_setprio(0);
        __builtin_amdgcn_s_barrier();
        __builtin_amdgcn_sched_barrier(0);

        // ---- P3: no reads; stage B-hi(t+2); MFMA Q11; boundary vmcnt ----
        if (pfB) {
            gload16(bS2, Bc + 8192 + wofs);
            gload16(bS3, Bc + 12288 + wofs);
            bS0 += 64; bS1 += 64; bS2 += 64; bS3 += 64;
        }
        __builtin_amdgcn_s_setprio(1);
#pragma unroll
        for (int kh = 0; kh < 2; ++kh)
#pragma unroll
            for (int mi = 0; mi < 4; ++mi)
#pragma unroll
                for (int nj = 0; nj < 2; ++nj)
                    acc[mi + 4][nj + 2] = __builtin_amdgcn_mfma_f32_16x16x32_bf16(aR[mi][kh], bR1[nj][kh], acc[mi + 4][nj + 2], 0, 0, 0);
        __builtin_amdgcn_s_setprio(0);
        if (pfB) asm volatile("s_waitcnt vmcnt(4)" ::: "memory");
        else     asm volatile("s_waitcnt vmcnt(0)" ::: "memory");
        __builtin_amdgcn_sched_barrier(0);
        __builtin_amdgcn_s_barrier();   // buffer swap: A(t+1),B(t+1) staged
        __builtin_amdgcn_sched_barrier(0);
    }

    if (o.flags & 1) {
        __hip_bfloat16* C = (__hip_bfloat16*)o.C;
#pragma unroll
        for (int i = 0; i < 8; ++i)
#pragma unroll
            for (int j = 0; j < 4; ++j)
#pragma unroll
                for (int r = 0; r < 4; ++r) {
                    int grow = row0 + wr * 128 + i * 16 + lq * 4 + r;
                    int gcol = col0 + wc * 64 + j * 16 + lm;
                    C[cb + (long long)grow * o.ldc + gcol] = __float2bfloat16(acc[i][j][r]);
                }
    } else {
        float* C = (float*)o.C;
#pragma unroll
        for (int i = 0; i < 8; ++i)
#pragma unroll
            for (int j = 0; j < 4; ++j)
#pragma unroll
                for (int r = 0; r < 4; ++r) {
                    int grow = row0 + wr * 128 + i * 16 + lq * 4 + r;
                    int gcol = col0 + wc * 64 + j * 16 + lm;
                    C[cb + (long long)grow * o.ldc + gcol] = acc[i][j][r];
                }
    }
}

// ---------------------------------------------------------------------------
// rmsnorm (fp32 in, bf16 out), one block per row
__global__ __launch_bounds__(256) void rmsnorm_kernel(const float* __restrict__ x,
                                                      const float* __restrict__ w,
                                                      __hip_bfloat16* __restrict__ out) {
    long long base = (long long)blockIdx.x * Dz;
    int t = threadIdx.x;
    float v[8];
    float ss = 0.f;
#pragma unroll
    for (int p = 0; p < 8; ++p) { v[p] = x[base + t + p * 256]; ss += v[p] * v[p]; }
    __shared__ float red[256];
    red[t] = ss; __syncthreads();
    for (int s2 = 128; s2 > 0; s2 >>= 1) { if (t < s2) red[t] += red[t + s2]; __syncthreads(); }
    float sc = rsqrtf(red[0] / (float)Dz + 1e-6f);
#pragma unroll
    for (int p = 0; p < 8; ++p) { int c = t + p * 256; out[base + c] = __float2bfloat16(v[p] * sc * w[c]); }
}

// xmean phase 1: partial sums over 64-row chunks. grid = B*8sc*8dc = 256
__global__ __launch_bounds__(256) void xmean_p1(const __hip_bfloat16* __restrict__ xn,
                                                float* __restrict__ xmp) {
    int blk = blockIdx.x;
    int b = blk >> 6, sc = (blk >> 3) & 7, dc = blk & 7;
    int t = threadIdx.x;
    int d = dc * 256 + t;
    const __hip_bfloat16* p = xn + (long long)b * Sz * Dz + (long long)sc * 64 * Dz + d;
    float s = 0.f;
    for (int si = 0; si < 64; ++si) s += __bfloat162float(p[(long long)si * Dz]);
    xmp[(b * 8 + sc) * Dz + d] = s;
}

// mlp1 with integrated mean-reduction: h[b,j]=silu(xm@wc1+bc1). grid = B*16 = 64
__global__ __launch_bounds__(256) void mlp1_kernel(const float* __restrict__ xmp,
                                                   const float* __restrict__ wc1,
                                                   const float* __restrict__ bc1,
                                                   float* __restrict__ h) {
    int blk = blockIdx.x;
    int b = blk >> 4, jb = blk & 15;
    int t = threadIdx.x;
    __shared__ float xs[Dz];
    __shared__ float red[8][32];
    const float* P = xmp + b * 8 * Dz;
#pragma unroll
    for (int p = 0; p < 8; ++p) {
        int d = t + p * 256;
        float s = 0.f;
#pragma unroll
        for (int q = 0; q < 8; ++q) s += P[q * Dz + d];
        xs[d] = s * (1.0f / (float)Sz);
    }
    __syncthreads();
    int j = jb * 32 + (t & 31), ksl = t >> 5;
    float s = 0.f;
    for (int k = ksl * 256; k < ksl * 256 + 256; ++k)
        s += xs[k] * wc1[(long long)k * 512 + j];
    red[ksl][t & 31] = s;
    __syncthreads();
    if (t < 32) {
        float tot = 0.f;
#pragma unroll
        for (int q = 0; q < 8; ++q) tot += red[q][t];
        tot += bc1[jb * 32 + t];
        h[b * 512 + jb * 32 + t] = tot / (1.0f + expf(-tot));
    }
}

// coeffs with k-split. grid = B*128 = 512
__global__ __launch_bounds__(256) void coeffs_kernel(const float* __restrict__ h,
                                                     const float* __restrict__ wc2,
                                                     const float* __restrict__ bc2,
                                                     float* __restrict__ coeffs) {
    int blk = blockIdx.x;
    int b = blk >> 7, ib = blk & 127;
    int t = threadIdx.x;
    int i = ib * 64 + (t & 63), ksl = t >> 6;
    const float* hb = h + b * 512;
    float s = 0.f;
    for (int k = ksl * 128; k < ksl * 128 + 128; ++k)
        s += hb[k] * wc2[(long long)k * 8192 + i];
    __shared__ float red[4][64];
    red[ksl][t & 63] = s;
    __syncthreads();
    if (t < 64) {
        int ii = ib * 64 + t;
        float tot = red[0][t] + red[1][t] + red[2][t] + red[3][t] + bc2[ii];
        int kdeg = (ii >> 8) & 3;
        coeffs[b * 8192 + ii] = tot * (0.1f / (float)(kdeg + 1));
    }
}

// Chebyshev path; xn bf16 in, cheby/kv bf16 out
__global__ __launch_bounds__(256) void cheby_kernel(const __hip_bfloat16* __restrict__ xn,
                                                    const float* __restrict__ coeffs,
                                                    __hip_bfloat16* __restrict__ cheby_out,
                                                    __hip_bfloat16* __restrict__ kv_src) {
    int bs = blockIdx.x;
    int b = bs >> 9;
    long long base = (long long)bs * Dz;
    int t = threadIdx.x;
    __shared__ float xrow[Dz];
    __shared__ float hsum[NHz][33];
    __shared__ float T[NHz][4];
#pragma unroll
    for (int p = 0; p < 8; ++p) xrow[t + p * 256] = __bfloat162float(xn[base + t + p * 256]);
    __syncthreads();
    int hh = t >> 5, lane = t & 31;
    float s = 0.f;
#pragma unroll
    for (int q = 0; q < 8; ++q) s += xrow[hh * HDz + lane + q * 32];
    hsum[hh][lane] = s;
    __syncthreads();
    if (t < NHz) {
        float tot = 0.f;
        for (int l2 = 0; l2 < 32; ++l2) tot += hsum[t][l2];
        float z = tanhf(tot / (float)HDz);
        float t2 = 2.f * z * z - 1.f;
        T[t][0] = 1.f; T[t][1] = z; T[t][2] = t2; T[t][3] = 2.f * z * t2 - z;
    }
    __syncthreads();
    const float* cbp = coeffs + (long long)b * (NHz * DEGz * HDz);
#pragma unroll
    for (int p = 0; p < 8; ++p) {
        int e = t + p * 256;
        int hd = e >> 8;
        int d = e & (HDz - 1);
        const float* ch = cbp + hd * (DEGz * HDz) + d;
        float co = T[hd][0] * ch[0] + T[hd][1] * ch[HDz] + T[hd][2] * ch[2 * HDz] + T[hd][3] * ch[3 * HDz];
        cheby_out[base + e] = __float2bfloat16(co);
        kv_src[base + e] = __float2bfloat16(xrow[e] + co);
    }
}

// softmax over 512-wide bf16 rows; applies causal mask itself
__global__ __launch_bounds__(128) void softmax_kernel(__hip_bfloat16* __restrict__ sc) {
    long long rid = blockIdx.x;
    int i = (int)(rid & (Sz - 1));
    long long base = rid * Sz;
    int t = threadIdx.x;
    float vals[4];
    float mx = -1e30f;
#pragma unroll
    for (int p = 0; p < 4; ++p) {
        int j = t + p * 128;
        float v = __bfloat162float(sc[base + j]);
        if (j > i) v = -1e9f;
        vals[p] = v;
        mx = fmaxf(mx, v);
    }
    __shared__ float red[128];
    red[t] = mx; __syncthreads();
    for (int s2 = 64; s2 > 0; s2 >>= 1) { if (t < s2) red[t] = fmaxf(red[t], red[t + s2]); __syncthreads(); }
    mx = red[0]; __syncthreads();
    float sum = 0.f;
#pragma unroll
    for (int p = 0; p < 4; ++p) { vals[p] = __expf(vals[p] - mx); sum += vals[p]; }
    red[t] = sum; __syncthreads();
    for (int s2 = 64; s2 > 0; s2 >>= 1) { if (t < s2) red[t] += red[t + s2]; __syncthreads(); }
    float inv = 1.0f / red[0];
#pragma unroll
    for (int p = 0; p < 4; ++p) sc[base + t + p * 128] = __float2bfloat16(vals[p] * inv);
}

// hcat = [rmsnorm(cheby,w_nc), rmsnorm(slr,w_ns)]
__global__ __launch_bounds__(256) void hcat_kernel(const __hip_bfloat16* __restrict__ cheby,
                                                   const __hip_bfloat16* __restrict__ slr,
                                                   const float* __restrict__ w_nc,
                                                   const float* __restrict__ w_ns,
                                                   __hip_bfloat16* __restrict__ hcat) {
    long long row = blockIdx.x;
    const __hip_bfloat16* c = cheby + row * Dz;
    const __hip_bfloat16* sl = slr + row * Dz;
    __hip_bfloat16* o = hcat + row * (2 * Dz);
    int t = threadIdx.x;
    float v1[8], v2[8];
    float ss1 = 0.f, ss2 = 0.f;
#pragma unroll
    for (int p = 0; p < 8; ++p) {
        v1[p] = __bfloat162float(c[t + p * 256]);  ss1 += v1[p] * v1[p];
        v2[p] = __bfloat162float(sl[t + p * 256]); ss2 += v2[p] * v2[p];
    }
    __shared__ float red[256];
    red[t] = ss1; __syncthreads();
    for (int s2 = 128; s2 > 0; s2 >>= 1) { if (t < s2) red[t] += red[t + s2]; __syncthreads(); }
    float sc1 = rsqrtf(red[0] / (float)Dz + 1e-6f);
    __syncthreads();
    red[t] = ss2; __syncthreads();
    for (int s2 = 128; s2 > 0; s2 >>= 1) { if (t < s2) red[t] += red[t + s2]; __syncthreads(); }
    float sc2 = rsqrtf(red[0] / (float)Dz + 1e-6f);
#pragma unroll
    for (int p = 0; p < 8; ++p) {
        int cx = t + p * 256;
        o[cx] = __float2bfloat16(v1[p] * sc1 * w_nc[cx]);
        o[Dz + cx] = __float2bfloat16(v2[p] * sc2 * w_ns[cx]);
    }
}

// fused = rmsnorm(silu(gate)*value, w_np) — gate/value are each the sum of two
// fp32 split-K partials (the gv GEMM's K-reduction folds in here)
__global__ __launch_bounds__(256) void fusedgate2_kernel(const float* __restrict__ p0g,
                                                         const float* __restrict__ p0v,
                                                         const float* __restrict__ p1g,
                                                         const float* __restrict__ p1v,
                                                         const float* __restrict__ w_np,
                                                         __hip_bfloat16* __restrict__ fused) {
    long long row = blockIdx.x;
    long long rb = row * Dz;
    __hip_bfloat16* o = fused + row * Dz;
    int t = threadIdx.x;
    float f[8];
    float ss = 0.f;
#pragma unroll
    for (int p = 0; p < 8; ++p) {
        int cx = t + p * 256;
        float ga = p0g[rb + cx] + p1g[rb + cx];
        float va = p0v[rb + cx] + p1v[rb + cx];
        float sv = ga / (1.0f + expf(-ga)) * va;
        f[p] = sv; ss += sv * sv;
    }
    __shared__ float red[256];
    red[t] = ss; __syncthreads();
    for (int s2 = 128; s2 > 0; s2 >>= 1) { if (t < s2) red[t] += red[t + s2]; __syncthreads(); }
    float sc = rsqrtf(red[0] / (float)Dz + 1e-6f);
#pragma unroll
    for (int p = 0; p < 8; ++p) { int cx = t + p * 256; o[cx] = __float2bfloat16(f[p] * sc * w_np[cx]); }
}

// ---------------------------------------------------------------------------
static GOp gop(const void* A, const void* B, void* C, const float* add,
               int K, int lda, int ldb, int ldc, int nbh, int nb, int gx, int gy,
               long long sAb, long long sAh, long long sBb, long long sBh,
               long long sCb, long long sCh, int flags) {
    GOp o;
    o.A = A; o.B = B; o.C = C; o.add = add;
    o.sAb = sAb; o.sAh = sAh; o.sBb = sBb; o.sBh = sBh; o.sCb = sCb; o.sCh = sCh;
    o.K = K; o.lda = lda; o.ldb = ldb; o.ldc = ldc; o.nbh = nbh;
    o.gx = gx; o.gy = gy; o.flags = flags;
    o.tileEnd = (flags & 32) ? gx * gy : nb * gx * gy;  // count; prefixed later
    return o;
}

static void launch_multi(hipStream_t st, GOp* ops, int n) {
    GArgs ga; ga.n = n;
    int acc = 0;
    for (int i = 0; i < n; ++i) { acc += ops[i].tileEnd; ga.op[i] = ops[i]; ga.op[i].tileEnd = acc; }
    hipLaunchKernelGGL(gemm_multi, dim3(acc), dim3(256), 0, st, ga);
}

static void launch_256(hipStream_t st, GOp* ops, int n) {
    GArgs ga; ga.n = n;
    int acc = 0;
    for (int i = 0; i < n; ++i) { acc += ops[i].tileEnd; ga.op[i] = ops[i]; ga.op[i].tileEnd = acc; }
    hipLaunchKernelGGL(gemm_256, dim3(acc), dim3(512), 0, st, ga);
}

extern "C" void kernel_launch(void* const* d_in, const int* in_sizes, int n_in,
                              void* d_out, int out_size, void* d_ws, size_t ws_size,
                              hipStream_t stream) {
    const float* x     = (const float*)d_in[0];
    const float* w_in  = (const float*)d_in[1];
    const float* wc1   = (const float*)d_in[6];
    const float* bc1   = (const float*)d_in[7];
    const float* wc2   = (const float*)d_in[8];
    const float* bc2   = (const float*)d_in[9];
    const float* wq    = (const float*)d_in[10];
    const float* wk    = (const float*)d_in[11];
    const float* wv    = (const float*)d_in[12];
    const float* wo    = (const float*)d_in[13];
    const float* w_nc  = (const float*)d_in[14];
    const float* w_ns  = (const float*)d_in[15];
    const float* w_fgv = (const float*)d_in[16];
    const float* w_np  = (const float*)d_in[17];
    const float* w_out = (const float*)d_in[18];
    float* out = (float*)d_out;

    const size_t MB = 1ull << 20;
    char* W = (char*)d_ws;
    __hip_bfloat16* xn_bf    = (__hip_bfloat16*)(W + 0 * MB);
    __hip_bfloat16* kv_bf    = (__hip_bfloat16*)(W + 8 * MB);
    __hip_bfloat16* cheby_bf = (__hip_bfloat16*)(W + 16 * MB);
    __hip_bfloat16* q_bf     = (__hip_bfloat16*)(W + 24 * MB);
    __hip_bfloat16* k_bf     = (__hip_bfloat16*)(W + 32 * MB);
    __hip_bfloat16* vT_bf    = (__hip_bfloat16*)(W + 40 * MB);
    __hip_bfloat16* o_bf     = (__hip_bfloat16*)(W + 48 * MB);
    __hip_bfloat16* scores   = (__hip_bfloat16*)(W + 56 * MB);   // 32MB
    __hip_bfloat16* wq_t     = (__hip_bfloat16*)(W + 88 * MB);
    __hip_bfloat16* wk_t     = (__hip_bfloat16*)(W + 96 * MB);
    __hip_bfloat16* wv_t     = (__hip_bfloat16*)(W + 104 * MB);
    __hip_bfloat16* wo_t     = (__hip_bfloat16*)(W + 112 * MB);
    __hip_bfloat16* wout_t   = (__hip_bfloat16*)(W + 120 * MB);
    // lifetime reuse (scores region becomes wfgv_t only AFTER PV has consumed it)
    __hip_bfloat16* wfgv_t   = (__hip_bfloat16*)(W + 56 * MB);
    __hip_bfloat16* slr_bf   = (__hip_bfloat16*)(W + 0 * MB);    // xn dead
    __hip_bfloat16* hcat_bf  = (__hip_bfloat16*)(W + 24 * MB);   // q,k dead (16MB)
    __hip_bfloat16* fused_bf = (__hip_bfloat16*)(W + 16 * MB);   // cheby dead after L12
    // gv split-K fp32 partials (16MB each), in regions dead at L13:
    float* p0g = (float*)(W + 0 * MB);    // slr dead after L12
    float* p0v = (float*)(W + 40 * MB);   // vT dead after L10, o dead after L11
    float* p1g = (float*)(W + 88 * MB);   // wq_t dead after L8
    float* p1v = (float*)(W + 104 * MB);  // wv_t dead after L7, wo_t dead after L11
    float* xmp   = (float*)(W + 128 * MB);                       // 8*B*D
    float* hbuf  = xmp + 65536;
    float* cbuf  = hbuf + 2048;

    const int BS = Bz * Sz;
    const long long SD = (long long)Sz * Dz;
    const long long SS = (long long)Sz * Sz;

    // L1: five 2048x2048 weight transposes in one launch
    {
        GOp ops[5];
        const float* srcs[5] = {wq, wk, wv, wo, w_out};
        __hip_bfloat16* dsts[5] = {wq_t, wk_t, wv_t, wo_t, wout_t};
        for (int i = 0; i < 5; ++i)
            ops[i] = gop(srcs[i], nullptr, dsts[i], nullptr, Dz, Dz, 0, Dz,
                         1, 1, 64, 64, 0, 0, 0, 0, 0, 0, 32);
        launch_multi(stream, ops, 5);
    }
    // L2: xn = rmsnorm(x)
    hipLaunchKernelGGL(rmsnorm_kernel, dim3(BS), dim3(256), 0, stream, x, w_in, xn_bf);
    // L3-L5: coeff path
    hipLaunchKernelGGL(xmean_p1, dim3(256), dim3(256), 0, stream, xn_bf, xmp);
    hipLaunchKernelGGL(mlp1_kernel, dim3(64), dim3(256), 0, stream, xmp, wc1, bc1, hbuf);
    hipLaunchKernelGGL(coeffs_kernel, dim3(512), dim3(256), 0, stream, hbuf, wc2, bc2, cbuf);
    // L6: cheby + kv_src
    hipLaunchKernelGGL(cheby_kernel, dim3(BS), dim3(256), 0, stream, xn_bf, cbuf, cheby_bf, kv_bf);
    // L7: q, k, vT via 256^2 GEMM (64+64+64 = 192 blocks)
    {
        GOp ops[3];
        ops[0] = gop(xn_bf, wq_t, q_bf, nullptr, Dz, Dz, Dz, Dz, 1, 1, 8, 8,
                     0, 0, 0, 0, 0, 0, 1);
        ops[1] = gop(kv_bf, wk_t, k_bf, nullptr, Dz, Dz, Dz, Dz, 1, 1, 8, 8,
                     0, 0, 0, 0, 0, 0, 1);
        ops[2] = gop(wv_t, kv_bf, vT_bf, nullptr, Dz, Dz, Dz, Sz, 1, Bz, 2, 8,
                     0, 0, SD, 0, (long long)Dz * Sz, 0, 1);
        launch_256(stream, ops, 3);
    }
    // L8: scores = q@k^T, scale+mask epilogue, skip masked tiles (legacy kernel)
    {
        GOp op = gop(q_bf, k_bf, scores, nullptr, AHDz, Dz, Dz, Sz, AHz, Bz * AHz, 4, 4,
                     SD, AHDz, SD, AHDz, (long long)AHz * SS, SS, 1 | 4);
        launch_multi(stream, &op, 1);
    }
    // L9: softmax (applies causal mask)
    hipLaunchKernelGGL(softmax_kernel, dim3(Bz * AHz * Sz), dim3(128), 0, stream, scores);
    // L10: PV alone (reads scores — nothing may write the scores region here!)
    {
        GOp op = gop(scores, vT_bf, o_bf, nullptr, Sz, Sz, Sz, Dz, AHz, Bz * AHz, 1, 4,
                     (long long)AHz * SS, SS, (long long)Dz * Sz, 128LL * Sz,
                     SD, 128, 1 | 8);
        launch_multi(stream, &op, 1);
    }
    // L11: slr = o @ wo (legacy, full-chip 256 blocks) + wfgv transpose in ONE
    // launch so the memory-bound transpose overlaps the compute-bound GEMM
    {
        GOp ops[2];
        ops[0] = gop(o_bf, wo_t, slr_bf, nullptr, Dz, Dz, Dz, Dz, 1, 1, 16, 16,
                     0, 0, 0, 0, 0, 0, 1);
        ops[1] = gop(w_fgv, nullptr, wfgv_t, nullptr, 2 * Dz, 2 * Dz, 0, 2 * Dz,
                     1, 1, 128, 128, 0, 0, 0, 0, 0, 0, 32);
        launch_multi(stream, ops, 2);
    }
    // L12: hcat
    hipLaunchKernelGGL(hcat_kernel, dim3(BS), dim3(256), 0, stream, cheby_bf, slr_bf, w_nc, w_ns, hcat_bf);
    // L13: gv = hcat @ w_fgv via 256^2 GEMM, split 4 ways (K-half x gate/value
    // N-half) = 4 x 64 = 256 blocks (exact chip fill); fp32 partials, the
    // K-reduction folds into fusedgate2.
    {
        const unsigned short* hc = (const unsigned short*)hcat_bf;
        const unsigned short* wf = (const unsigned short*)wfgv_t;
        GOp ops[4];
        ops[0] = gop(hc,        wf,                      p0g, nullptr, Dz, 2 * Dz, 2 * Dz, Dz,
                     1, 1, 8, 8, 0, 0, 0, 0, 0, 0, 0);
        ops[1] = gop(hc,        wf + 2048LL * 4096,      p0v, nullptr, Dz, 2 * Dz, 2 * Dz, Dz,
                     1, 1, 8, 8, 0, 0, 0, 0, 0, 0, 0);
        ops[2] = gop(hc + 2048, wf + 2048,               p1g, nullptr, Dz, 2 * Dz, 2 * Dz, Dz,
                     1, 1, 8, 8, 0, 0, 0, 0, 0, 0, 0);
        ops[3] = gop(hc + 2048, wf + 2048LL * 4096 + 2048, p1v, nullptr, Dz, 2 * Dz, 2 * Dz, Dz,
                     1, 1, 8, 8, 0, 0, 0, 0, 0, 0, 0);
        launch_256(stream, ops, 4);
    }
    // L14: fused gate (+ gv K-reduction)
    hipLaunchKernelGGL(fusedgate2_kernel, dim3(BS), dim3(256), 0, stream,
                       p0g, p0v, p1g, p1v, w_np, fused_bf);
    // L15: out = x + fused @ w_out (legacy, full-chip 256 blocks)
    {
        GOp op = gop(fused_bf, wout_t, out, x, Dz, Dz, Dz, Dz, 1, 1, 16, 16,
                     0, 0, 0, 0, 0, 0, 2);
        launch_multi(stream, &op, 1);
    }
}

// Round 6
// 536.905 us; speedup vs baseline: 1.1878x; 1.0724x over previous
//
#include <hip/hip_runtime.h>
#include <hip/hip_bf16.h>
#include <math.h>

#define Bz 4
#define Sz 512
#define Dz 2048
#define NHz 8
#define DEGz 4
#define HDz 256
#define AHz 16
#define AHDz 128
#define SCALE_ATT 0.08838834764831845f  // 1/sqrt(128)

typedef __attribute__((ext_vector_type(8))) short short8;
typedef __attribute__((ext_vector_type(4))) float f32x4;

#define AS1 __attribute__((address_space(1)))
#define AS3 __attribute__((address_space(3)))

__device__ inline void gload16(const void* g, void* l) {
    __builtin_amdgcn_global_load_lds((const AS1 void*)g, (AS3 void*)l, 16, 0, 0);
}

// ---------------------------------------------------------------------------
// Multi-op GEMM/transpose dispatcher (legacy 128x128 structure).
// GEMM op: C[m][n] = sum_k A[m][k]*BT[n][k].
// flags: 1=bf16 out, 2=fp32 residual add, 4=score epilogue (scale+causal,
//        skip fully-masked tiles), 8=causal K-limit (kEnd=row0+128),
//        32=transpose+cvt op (A=fp32 src, C=bf16 dst), 128x128 tiles:
//        read 512B bursts (float4 x 32 lanes), write 256B bursts (ushort8 x
//        16 lanes), bf16 stored in a 32KB XOR-swizzled LDS tile (chunk-col
//        ^= (row>>3)&7) so the column-gather on the write side is ~4-way
//        instead of fully serialized.
struct GOp {
    const void* A; const void* B; void* C; const float* add;
    long long sAb, sAh, sBb, sBh, sCb, sCh;
    int K, lda, ldb, ldc, nbh, gx, gy, flags, tileEnd;
};
struct GArgs { int n; GOp op[6]; };

__global__ __launch_bounds__(256) void gemm_multi(GArgs ga) {
    __shared__ __align__(16) unsigned short SMEM[16384];  // 32KB unified
    unsigned short* As = SMEM;          // legacy: 2*128*32 shorts (16KB)
    unsigned short* Bs = SMEM + 8192;   // legacy: 2*128*32 shorts (16KB)

    int tid = blockIdx.x;
    int oi = 0;
    while (tid >= ga.op[oi].tileEnd) ++oi;
    GOp o = ga.op[oi];
    int local = tid - (oi ? ga.op[oi - 1].tileEnd : 0);
    int t = threadIdx.x;

    if (o.flags & 32) {
        // 128x128 transpose + fp32->bf16, swizzled bf16 LDS tile
        const float* src = (const float*)o.A;
        unsigned short* dst = (unsigned short*)o.C;
        int ty = local / o.gx, tx = local - ty * o.gx;
        int k0 = ty * 128, n0 = tx * 128;
        unsigned short* tile = SMEM;  // [128 rows][16 chunks of 8 bf16] swizzled

        int c32 = t & 31, r8 = t >> 5;   // read: 32 lanes x float4 per row
#pragma unroll
        for (int p = 0; p < 16; ++p) {
            int r = r8 + p * 8;
            f32x4 v = *(const f32x4*)(src + (long long)(k0 + r) * o.lda + n0 + c32 * 4);
            // elements n = 4*c32 .. 4*c32+3 -> chunk (c32>>1) ^ ((r>>3)&7)
            int chunk = (c32 >> 1) ^ ((r >> 3) & 7);
            __hip_bfloat16* tb = (__hip_bfloat16*)(tile + r * 128 + chunk * 8 + (c32 & 1) * 4);
            tb[0] = __float2bfloat16(v[0]);
            tb[1] = __float2bfloat16(v[1]);
            tb[2] = __float2bfloat16(v[2]);
            tb[3] = __float2bfloat16(v[3]);
        }
        __syncthreads();
        int l16 = t & 15, rw = t >> 4;   // write: 16 lanes x ushort8 per n-row
#pragma unroll
        for (int p = 0; p < 8; ++p) {
            int n = rw + p * 16;
            int nc = n >> 3, nо = n & 7;
            union { short8 s; unsigned short u[8]; } o8;
#pragma unroll
            for (int j = 0; j < 8; ++j) {
                int kk = l16 * 8 + j;
                o8.u[j] = tile[kk * 128 + ((nc ^ ((kk >> 3) & 7)) * 8) + nо];
            }
            *(short8*)(dst + (long long)(n0 + n) * o.ldc + k0 + l16 * 8) = o8.s;
        }
        return;
    }

    int perOp = o.gx * o.gy;
    int batch = local / perOp;
    int r3 = local - batch * perOp;
    int ty = r3 / o.gx;
    int tx = r3 - ty * o.gx;
    int row0 = ty * 128, col0 = tx * 128;

    if ((o.flags & 4) && (col0 > row0 + 127)) return;  // fully masked: softmax masks

    int zb = batch / o.nbh, zh = batch - zb * o.nbh;
    long long cb = (long long)zb * o.sCb + (long long)zh * o.sCh;

    int kEnd = o.K;
    if (o.flags & 8) { int ke = row0 + 128; kEnd = kEnd < ke ? kEnd : ke; }

    const unsigned short* Ab = (const unsigned short*)o.A + zb * o.sAb + zh * o.sAh;
    const unsigned short* Bb = (const unsigned short*)o.B + zb * o.sBb + zh * o.sBh;

    int w = t >> 6, l = t & 63;
    int lrow = l >> 2;
    int lchunk = (l & 3) * 8;

    const unsigned short* aP0 = Ab + (long long)(row0 + w * 16 + lrow) * o.lda + lchunk;
    const unsigned short* aP1 = aP0 + 64LL * o.lda;
    const unsigned short* bP0 = Bb + (long long)(col0 + w * 16 + lrow) * o.ldb + lchunk;
    const unsigned short* bP1 = bP0 + 64LL * o.ldb;
    unsigned short* aL0 = As + w * 512;
    unsigned short* aL1 = As + (w + 4) * 512;
    unsigned short* bL0 = Bs + w * 512;
    unsigned short* bL1 = Bs + (w + 4) * 512;

    int lm = l & 15, lq = l >> 4;
    int wr = (w >> 1) * 64, wc = (w & 1) * 64;

    f32x4 acc[4][4];
#pragma unroll
    for (int i = 0; i < 4; ++i)
#pragma unroll
        for (int j = 0; j < 4; ++j) acc[i][j] = (f32x4){0.f, 0.f, 0.f, 0.f};

    for (int k0 = 0; k0 < kEnd; k0 += 64) {
        gload16(aP0, aL0);
        gload16(aP1, aL1);
        gload16(bP0, bL0);
        gload16(bP1, bL1);
        gload16(aP0 + 32, aL0 + 4096);
        gload16(aP1 + 32, aL1 + 4096);
        gload16(bP0 + 32, bL0 + 4096);
        gload16(bP1 + 32, bL1 + 4096);
        aP0 += 64; aP1 += 64; bP0 += 64; bP1 += 64;
        __syncthreads();

#pragma unroll
        for (int h = 0; h < 2; ++h) {
            const unsigned short* Ah = As + h * 4096;
            const unsigned short* Bh = Bs + h * 4096;
            short8 af[4], bfr[4];
#pragma unroll
            for (int i = 0; i < 4; ++i)
                af[i] = *(const short8*)(Ah + (wr + i * 16 + lm) * 32 + lq * 8);
#pragma unroll
            for (int j = 0; j < 4; ++j)
                bfr[j] = *(const short8*)(Bh + (wc + j * 16 + lm) * 32 + lq * 8);
#pragma unroll
            for (int i = 0; i < 4; ++i)
#pragma unroll
                for (int j = 0; j < 4; ++j)
                    acc[i][j] = __builtin_amdgcn_mfma_f32_16x16x32_bf16(af[i], bfr[j], acc[i][j], 0, 0, 0);
        }
        __syncthreads();
    }

    if (o.flags & 1) {
        __hip_bfloat16* C = (__hip_bfloat16*)o.C;
#pragma unroll
        for (int i = 0; i < 4; ++i)
#pragma unroll
            for (int j = 0; j < 4; ++j)
#pragma unroll
                for (int r = 0; r < 4; ++r) {
                    int grow = row0 + wr + i * 16 + lq * 4 + r;
                    int gcol = col0 + wc + j * 16 + lm;
                    float v = acc[i][j][r];
                    if (o.flags & 4) v = (gcol > grow) ? -1e9f : v * SCALE_ATT;
                    C[cb + (long long)grow * o.ldc + gcol] = __float2bfloat16(v);
                }
    } else {
        float* C = (float*)o.C;
#pragma unroll
        for (int i = 0; i < 4; ++i)
#pragma unroll
            for (int j = 0; j < 4; ++j)
#pragma unroll
                for (int r = 0; r < 4; ++r) {
                    int grow = row0 + wr + i * 16 + lq * 4 + r;
                    int gcol = col0 + wc + j * 16 + lm;
                    float v = acc[i][j][r];
                    long long ci = cb + (long long)grow * o.ldc + gcol;
                    if (o.flags & 2) v += o.add[ci];
                    C[ci] = v;
                }
    }
}

// ---------------------------------------------------------------------------
// 256x256 8-phase GEMM (m201 geometry): BK=64, 512 threads (8 waves = 2Mx4N,
// per-wave output 128x64), 128KB double-buffered LDS. Per K-tile, 4 phases:
//   { ds-read quadrant frags || stage (2 gload16) -> lgkmcnt(0) (own reads)
//     -> sched_barrier -> setprio(1) 16 MFMA setprio(0) -> s_barrier }.
// NO barrier before the MFMA cluster: each wave gates its MFMA only on its
// OWN lgkmcnt, so waves skew within a phase and the LDS-read pipe overlaps
// the MFMA pipe across waves (round-5 change, +measured). Invariants:
//  (a) P2 stages B(t+2) into CURRENT buf B only after end-P1 barrier, by which
//      every wave drained its B reads (its P1 lgkmcnt(0));
//  (b) buffer swap at end-P3 with vmcnt(4): A(t+1),B(t+1) complete, B(t+2)'s
//      4 loads stay in flight (counted, never 0 mid-loop).
// sched_barrier(0) after every s_barrier pins memory ops inside their phase.
// T2 XOR swizzle via pre-swizzled global source + swizzled ds_read (verified:
// SQ_LDS_BANK_CONFLICT==0 rounds 1-5).
// flags: 1=bf16 out, else fp32 out. Requires M%256==0, N%256==0, K%64==0.
__global__ __launch_bounds__(512) void gemm_256(GArgs ga) {
    __shared__ unsigned short LA[2][256 * 64];   // 2 x 32KB
    __shared__ unsigned short LB[2][256 * 64];   // 2 x 32KB

    int tid = blockIdx.x;
    int oi = 0;
    while (tid >= ga.op[oi].tileEnd) ++oi;
    GOp o = ga.op[oi];
    int local = tid - (oi ? ga.op[oi - 1].tileEnd : 0);
    int t = threadIdx.x;

    int perOp = o.gx * o.gy;
    int batch = local / perOp;
    int r3 = local - batch * perOp;
    int ty = r3 / o.gx, tx = r3 - ty * o.gx;
    int row0 = ty * 256, col0 = tx * 256;

    int zb = batch / o.nbh, zh = batch - zb * o.nbh;
    long long cb = (long long)zb * o.sCb + (long long)zh * o.sCh;

    const unsigned short* Ab = (const unsigned short*)o.A + zb * o.sAb + zh * o.sAh;
    const unsigned short* Bb = (const unsigned short*)o.B + zb * o.sBb + zh * o.sBh;

    int w = t >> 6, l = t & 63;
    // Stage addressing (verified r1): unit = 64 rows x 64 shorts (8KB), one
    // gload16/thread/unit. row-in-unit = w*8 + (l>>3); swizzled source col16
    // = (l&7)^(l>>3), LDS col-group = l&7. Coalescing preserved (perm within
    // 128B row segments).
    int srow = w * 8 + (l >> 3);
    int scol = ((l & 7) ^ (l >> 3)) << 3;   // shorts

    const unsigned short* aS0 = Ab + (long long)(row0 + srow) * o.lda + scol;
    const unsigned short* aS1 = Ab + (long long)(row0 + 64 + srow) * o.lda + scol;
    const unsigned short* aS2 = Ab + (long long)(row0 + 128 + srow) * o.lda + scol;
    const unsigned short* aS3 = Ab + (long long)(row0 + 192 + srow) * o.lda + scol;
    const unsigned short* bS0 = Bb + (long long)(col0 + srow) * o.ldb + scol;
    const unsigned short* bS1 = Bb + (long long)(col0 + 64 + srow) * o.ldb + scol;
    const unsigned short* bS2 = Bb + (long long)(col0 + 128 + srow) * o.ldb + scol;
    const unsigned short* bS3 = Bb + (long long)(col0 + 192 + srow) * o.ldb + scol;

    int wofs = w * 512;  // shorts; HW adds lane*16B

    int nkt = o.K >> 6;

    // prologue: B(0) -> LB[0], A(0) -> LA[0], B(1) -> LB[1]
    gload16(bS0, &LB[0][wofs]);
    gload16(bS1, &LB[0][4096 + wofs]);
    gload16(bS2, &LB[0][8192 + wofs]);
    gload16(bS3, &LB[0][12288 + wofs]);
    gload16(aS0, &LA[0][wofs]);
    gload16(aS1, &LA[0][4096 + wofs]);
    gload16(aS2, &LA[0][8192 + wofs]);
    gload16(aS3, &LA[0][12288 + wofs]);
    aS0 += 64; aS1 += 64; aS2 += 64; aS3 += 64;
    if (nkt > 1) {
        gload16(bS0 + 64, &LB[1][wofs]);
        gload16(bS1 + 64, &LB[1][4096 + wofs]);
        gload16(bS2 + 64, &LB[1][8192 + wofs]);
        gload16(bS3 + 64, &LB[1][12288 + wofs]);
    }
    bS0 += 128; bS1 += 128; bS2 += 128; bS3 += 128;
    if (nkt > 1) asm volatile("s_waitcnt vmcnt(4)" ::: "memory");
    else         asm volatile("s_waitcnt vmcnt(0)" ::: "memory");
    __builtin_amdgcn_s_barrier();
    __builtin_amdgcn_sched_barrier(0);

    int lm = l & 15, lq = l >> 4;
    int wr = w >> 2, wc = w & 3;      // 2x4 wave grid
    int c0 = ((lq) ^ (lm & 7)) << 3;
    int c1 = ((4 + lq) ^ (lm & 7)) << 3;

    f32x4 acc[8][4];
#pragma unroll
    for (int i = 0; i < 8; ++i)
#pragma unroll
        for (int j = 0; j < 4; ++j) acc[i][j] = (f32x4){0.f, 0.f, 0.f, 0.f};

    for (int kt = 0; kt < nkt; ++kt) {
        unsigned short* Ac = &LA[kt & 1][0];
        unsigned short* Bc = &LB[kt & 1][0];
        unsigned short* An = &LA[(kt & 1) ^ 1][0];
        bool pfA = (kt + 1 < nkt);
        bool pfB = (kt + 2 < nkt);

        short8 aR[4][2], bR0[2][2], bR1[2][2];

        // ---- P0: read A(m0-3)+B(n0-1); stage A-lo(t+1); MFMA Q00 ----
#pragma unroll
        for (int mi = 0; mi < 4; ++mi) {
            const unsigned short* ar = Ac + (wr * 128 + mi * 16 + lm) * 64;
            aR[mi][0] = *(const short8*)(ar + c0);
            aR[mi][1] = *(const short8*)(ar + c1);
        }
#pragma unroll
        for (int nj = 0; nj < 2; ++nj) {
            const unsigned short* br = Bc + (wc * 64 + nj * 16 + lm) * 64;
            bR0[nj][0] = *(const short8*)(br + c0);
            bR0[nj][1] = *(const short8*)(br + c1);
        }
        if (pfA) {
            gload16(aS0, An + wofs);
            gload16(aS1, An + 4096 + wofs);
        }
        asm volatile("s_waitcnt lgkmcnt(0)" ::: "memory");
        __builtin_amdgcn_sched_barrier(0);
        __builtin_amdgcn_s_setprio(1);
#pragma unroll
        for (int kh = 0; kh < 2; ++kh)
#pragma unroll
            for (int mi = 0; mi < 4; ++mi)
#pragma unroll
                for (int nj = 0; nj < 2; ++nj)
                    acc[mi][nj] = __builtin_amdgcn_mfma_f32_16x16x32_bf16(aR[mi][kh], bR0[nj][kh], acc[mi][nj], 0, 0, 0);
        __builtin_amdgcn_s_setprio(0);
        __builtin_amdgcn_s_barrier();
        __builtin_amdgcn_sched_barrier(0);

        // ---- P1: read B(n2-3); stage A-hi(t+1); MFMA Q01 ----
#pragma unroll
        for (int nj = 0; nj < 2; ++nj) {
            const unsigned short* br = Bc + (wc * 64 + (nj + 2) * 16 + lm) * 64;
            bR1[nj][0] = *(const short8*)(br + c0);
            bR1[nj][1] = *(const short8*)(br + c1);
        }
        if (pfA) {
            gload16(aS2, An + 8192 + wofs);
            gload16(aS3, An + 12288 + wofs);
            aS0 += 64; aS1 += 64; aS2 += 64; aS3 += 64;
        }
        asm volatile("s_waitcnt lgkmcnt(0)" ::: "memory");
        __builtin_amdgcn_sched_barrier(0);
        __builtin_amdgcn_s_setprio(1);
#pragma unroll
        for (int kh = 0; kh < 2; ++kh)
#pragma unroll
            for (int mi = 0; mi < 4; ++mi)
#pragma unroll
                for (int nj = 0; nj < 2; ++nj)
                    acc[mi][nj + 2] = __builtin_amdgcn_mfma_f32_16x16x32_bf16(aR[mi][kh], bR1[nj][kh], acc[mi][nj + 2], 0, 0, 0);
        __builtin_amdgcn_s_setprio(0);
        __builtin_amdgcn_s_barrier();   // B reads of tile t drained by all waves
        __builtin_amdgcn_sched_barrier(0);

        // ---- P2: read A(m4-7) (reuse aR); stage B-lo(t+2) into CURRENT buf
        //      (B region dead after end-P1 barrier); MFMA Q10 ----
#pragma unroll
        for (int mi = 0; mi < 4; ++mi) {
            const unsigned short* ar = Ac + (wr * 128 + (mi + 4) * 16 + lm) * 64;
            aR[mi][0] = *(const short8*)(ar + c0);
            aR[mi][1] = *(const short8*)(ar + c1);
        }
        if (pfB) {
            gload16(bS0, Bc + wofs);
            gload16(bS1, Bc + 4096 + wofs);
        }
        asm volatile("s_waitcnt lgkmcnt(0)" ::: "memory");
        __builtin_amdgcn_sched_barrier(0);
        __builtin_amdgcn_s_setprio(1);
#pragma unroll
        for (int kh = 0; kh < 2; ++kh)
#pragma unroll
            for (int mi = 0; mi < 4; ++mi)
#pragma unroll
                for (int nj = 0; nj < 2; ++nj)
                    acc[mi + 4][nj] = __builtin_amdgcn_mfma_f32_16x16x32_bf16(aR[mi][kh], bR0[nj][kh], acc[mi + 4][nj], 0, 0, 0);
        __builtin_amdgcn_s_setprio(0);
        __builtin_amdgcn_s_barrier();
        __builtin_amdgcn_sched_barrier(0);

        // ---- P3: no reads; stage B-hi(t+2); MFMA Q11; boundary vmcnt ----
        if (pfB) {
            gload16(bS2, Bc + 8192 + wofs);
            gload16(bS3, Bc + 12288 + wofs);
            bS0 += 64; bS1 += 64; bS2 += 64; bS3 += 64;
        }
        __builtin_amdgcn_s_setprio(1);
#pragma unroll
        for (int kh = 0; kh < 2; ++kh)
#pragma unroll
            for (int mi = 0; mi < 4; ++mi)
#pragma unroll
                for (int nj = 0; nj < 2; ++nj)
                    acc[mi + 4][nj + 2] = __builtin_amdgcn_mfma_f32_16x16x32_bf16(aR[mi][kh], bR1[nj][kh], acc[mi + 4][nj + 2], 0, 0, 0);
        __builtin_amdgcn_s_setprio(0);
        if (pfB) asm volatile("s_waitcnt vmcnt(4)" ::: "memory");
        else     asm volatile("s_waitcnt vmcnt(0)" ::: "memory");
        __builtin_amdgcn_sched_barrier(0);
        __builtin_amdgcn_s_barrier();   // buffer swap: A(t+1),B(t+1) staged
        __builtin_amdgcn_sched_barrier(0);
    }

    if (o.flags & 1) {
        __hip_bfloat16* C = (__hip_bfloat16*)o.C;
#pragma unroll
        for (int i = 0; i < 8; ++i)
#pragma unroll
            for (int j = 0; j < 4; ++j)
#pragma unroll
                for (int r = 0; r < 4; ++r) {
                    int grow = row0 + wr * 128 + i * 16 + lq * 4 + r;
                    int gcol = col0 + wc * 64 + j * 16 + lm;
                    C[cb + (long long)grow * o.ldc + gcol] = __float2bfloat16(acc[i][j][r]);
                }
    } else {
        float* C = (float*)o.C;
#pragma unroll
        for (int i = 0; i < 8; ++i)
#pragma unroll
            for (int j = 0; j < 4; ++j)
#pragma unroll
                for (int r = 0; r < 4; ++r) {
                    int grow = row0 + wr * 128 + i * 16 + lq * 4 + r;
                    int gcol = col0 + wc * 64 + j * 16 + lm;
                    C[cb + (long long)grow * o.ldc + gcol] = acc[i][j][r];
                }
    }
}

// ---------------------------------------------------------------------------
// rmsnorm (fp32 in, bf16 out), one block per row
__global__ __launch_bounds__(256) void rmsnorm_kernel(const float* __restrict__ x,
                                                      const float* __restrict__ w,
                                                      __hip_bfloat16* __restrict__ out) {
    long long base = (long long)blockIdx.x * Dz;
    int t = threadIdx.x;
    float v[8];
    float ss = 0.f;
#pragma unroll
    for (int p = 0; p < 8; ++p) { v[p] = x[base + t + p * 256]; ss += v[p] * v[p]; }
    __shared__ float red[256];
    red[t] = ss; __syncthreads();
    for (int s2 = 128; s2 > 0; s2 >>= 1) { if (t < s2) red[t] += red[t + s2]; __syncthreads(); }
    float sc = rsqrtf(red[0] / (float)Dz + 1e-6f);
#pragma unroll
    for (int p = 0; p < 8; ++p) { int c = t + p * 256; out[base + c] = __float2bfloat16(v[p] * sc * w[c]); }
}

// xmean phase 1: partial sums over 64-row chunks. grid = B*8sc*8dc = 256
__global__ __launch_bounds__(256) void xmean_p1(const __hip_bfloat16* __restrict__ xn,
                                                float* __restrict__ xmp) {
    int blk = blockIdx.x;
    int b = blk >> 6, sc = (blk >> 3) & 7, dc = blk & 7;
    int t = threadIdx.x;
    int d = dc * 256 + t;
    const __hip_bfloat16* p = xn + (long long)b * Sz * Dz + (long long)sc * 64 * Dz + d;
    float s = 0.f;
    for (int si = 0; si < 64; ++si) s += __bfloat162float(p[(long long)si * Dz]);
    xmp[(b * 8 + sc) * Dz + d] = s;
}

// mlp1 with integrated mean-reduction: h[b,j]=silu(xm@wc1+bc1). grid = B*16 = 64
__global__ __launch_bounds__(256) void mlp1_kernel(const float* __restrict__ xmp,
                                                   const float* __restrict__ wc1,
                                                   const float* __restrict__ bc1,
                                                   float* __restrict__ h) {
    int blk = blockIdx.x;
    int b = blk >> 4, jb = blk & 15;
    int t = threadIdx.x;
    __shared__ float xs[Dz];
    __shared__ float red[8][32];
    const float* P = xmp + b * 8 * Dz;
#pragma unroll
    for (int p = 0; p < 8; ++p) {
        int d = t + p * 256;
        float s = 0.f;
#pragma unroll
        for (int q = 0; q < 8; ++q) s += P[q * Dz + d];
        xs[d] = s * (1.0f / (float)Sz);
    }
    __syncthreads();
    int j = jb * 32 + (t & 31), ksl = t >> 5;
    float s = 0.f;
    for (int k = ksl * 256; k < ksl * 256 + 256; ++k)
        s += xs[k] * wc1[(long long)k * 512 + j];
    red[ksl][t & 31] = s;
    __syncthreads();
    if (t < 32) {
        float tot = 0.f;
#pragma unroll
        for (int q = 0; q < 8; ++q) tot += red[q][t];
        tot += bc1[jb * 32 + t];
        h[b * 512 + jb * 32 + t] = tot / (1.0f + expf(-tot));
    }
}

// coeffs with k-split. grid = B*128 = 512
__global__ __launch_bounds__(256) void coeffs_kernel(const float* __restrict__ h,
                                                     const float* __restrict__ wc2,
                                                     const float* __restrict__ bc2,
                                                     float* __restrict__ coeffs) {
    int blk = blockIdx.x;
    int b = blk >> 7, ib = blk & 127;
    int t = threadIdx.x;
    int i = ib * 64 + (t & 63), ksl = t >> 6;
    const float* hb = h + b * 512;
    float s = 0.f;
    for (int k = ksl * 128; k < ksl * 128 + 128; ++k)
        s += hb[k] * wc2[(long long)k * 8192 + i];
    __shared__ float red[4][64];
    red[ksl][t & 63] = s;
    __syncthreads();
    if (t < 64) {
        int ii = ib * 64 + t;
        float tot = red[0][t] + red[1][t] + red[2][t] + red[3][t] + bc2[ii];
        int kdeg = (ii >> 8) & 3;
        coeffs[b * 8192 + ii] = tot * (0.1f / (float)(kdeg + 1));
    }
}

// Chebyshev path; xn bf16 in, cheby/kv bf16 out
__global__ __launch_bounds__(256) void cheby_kernel(const __hip_bfloat16* __restrict__ xn,
                                                    const float* __restrict__ coeffs,
                                                    __hip_bfloat16* __restrict__ cheby_out,
                                                    __hip_bfloat16* __restrict__ kv_src) {
    int bs = blockIdx.x;
    int b = bs >> 9;
    long long base = (long long)bs * Dz;
    int t = threadIdx.x;
    __shared__ float xrow[Dz];
    __shared__ float hsum[NHz][33];
    __shared__ float T[NHz][4];
#pragma unroll
    for (int p = 0; p < 8; ++p) xrow[t + p * 256] = __bfloat162float(xn[base + t + p * 256]);
    __syncthreads();
    int hh = t >> 5, lane = t & 31;
    float s = 0.f;
#pragma unroll
    for (int q = 0; q < 8; ++q) s += xrow[hh * HDz + lane + q * 32];
    hsum[hh][lane] = s;
    __syncthreads();
    if (t < NHz) {
        float tot = 0.f;
        for (int l2 = 0; l2 < 32; ++l2) tot += hsum[t][l2];
        float z = tanhf(tot / (float)HDz);
        float t2 = 2.f * z * z - 1.f;
        T[t][0] = 1.f; T[t][1] = z; T[t][2] = t2; T[t][3] = 2.f * z * t2 - z;
    }
    __syncthreads();
    const float* cbp = coeffs + (long long)b * (NHz * DEGz * HDz);
#pragma unroll
    for (int p = 0; p < 8; ++p) {
        int e = t + p * 256;
        int hd = e >> 8;
        int d = e & (HDz - 1);
        const float* ch = cbp + hd * (DEGz * HDz) + d;
        float co = T[hd][0] * ch[0] + T[hd][1] * ch[HDz] + T[hd][2] * ch[2 * HDz] + T[hd][3] * ch[3 * HDz];
        cheby_out[base + e] = __float2bfloat16(co);
        kv_src[base + e] = __float2bfloat16(xrow[e] + co);
    }
}

// softmax over 512-wide bf16 rows; applies causal mask itself
__global__ __launch_bounds__(128) void softmax_kernel(__hip_bfloat16* __restrict__ sc) {
    long long rid = blockIdx.x;
    int i = (int)(rid & (Sz - 1));
    long long base = rid * Sz;
    int t = threadIdx.x;
    float vals[4];
    float mx = -1e30f;
#pragma unroll
    for (int p = 0; p < 4; ++p) {
        int j = t + p * 128;
        float v = __bfloat162float(sc[base + j]);
        if (j > i) v = -1e9f;
        vals[p] = v;
        mx = fmaxf(mx, v);
    }
    __shared__ float red[128];
    red[t] = mx; __syncthreads();
    for (int s2 = 64; s2 > 0; s2 >>= 1) { if (t < s2) red[t] = fmaxf(red[t], red[t + s2]); __syncthreads(); }
    mx = red[0]; __syncthreads();
    float sum = 0.f;
#pragma unroll
    for (int p = 0; p < 4; ++p) { vals[p] = __expf(vals[p] - mx); sum += vals[p]; }
    red[t] = sum; __syncthreads();
    for (int s2 = 64; s2 > 0; s2 >>= 1) { if (t < s2) red[t] += red[t + s2]; __syncthreads(); }
    float inv = 1.0f / red[0];
#pragma unroll
    for (int p = 0; p < 4; ++p) sc[base + t + p * 128] = __float2bfloat16(vals[p] * inv);
}

// hcat = [rmsnorm(cheby,w_nc), rmsnorm(slr,w_ns)]
__global__ __launch_bounds__(256) void hcat_kernel(const __hip_bfloat16* __restrict__ cheby,
                                                   const __hip_bfloat16* __restrict__ slr,
                                                   const float* __restrict__ w_nc,
                                                   const float* __restrict__ w_ns,
                                                   __hip_bfloat16* __restrict__ hcat) {
    long long row = blockIdx.x;
    const __hip_bfloat16* c = cheby + row * Dz;
    const __hip_bfloat16* sl = slr + row * Dz;
    __hip_bfloat16* o = hcat + row * (2 * Dz);
    int t = threadIdx.x;
    float v1[8], v2[8];
    float ss1 = 0.f, ss2 = 0.f;
#pragma unroll
    for (int p = 0; p < 8; ++p) {
        v1[p] = __bfloat162float(c[t + p * 256]);  ss1 += v1[p] * v1[p];
        v2[p] = __bfloat162float(sl[t + p * 256]); ss2 += v2[p] * v2[p];
    }
    __shared__ float red[256];
    red[t] = ss1; __syncthreads();
    for (int s2 = 128; s2 > 0; s2 >>= 1) { if (t < s2) red[t] += red[t + s2]; __syncthreads(); }
    float sc1 = rsqrtf(red[0] / (float)Dz + 1e-6f);
    __syncthreads();
    red[t] = ss2; __syncthreads();
    for (int s2 = 128; s2 > 0; s2 >>= 1) { if (t < s2) red[t] += red[t + s2]; __syncthreads(); }
    float sc2 = rsqrtf(red[0] / (float)Dz + 1e-6f);
#pragma unroll
    for (int p = 0; p < 8; ++p) {
        int cx = t + p * 256;
        o[cx] = __float2bfloat16(v1[p] * sc1 * w_nc[cx]);
        o[Dz + cx] = __float2bfloat16(v2[p] * sc2 * w_ns[cx]);
    }
}

// fused = rmsnorm(silu(gate)*value, w_np) — gate/value are each the sum of two
// fp32 split-K partials (the gv GEMM's K-reduction folds in here)
__global__ __launch_bounds__(256) void fusedgate2_kernel(const float* __restrict__ p0g,
                                                         const float* __restrict__ p0v,
                                                         const float* __restrict__ p1g,
                                                         const float* __restrict__ p1v,
                                                         const float* __restrict__ w_np,
                                                         __hip_bfloat16* __restrict__ fused) {
    long long row = blockIdx.x;
    long long rb = row * Dz;
    __hip_bfloat16* o = fused + row * Dz;
    int t = threadIdx.x;
    float f[8];
    float ss = 0.f;
#pragma unroll
    for (int p = 0; p < 8; ++p) {
        int cx = t + p * 256;
        float ga = p0g[rb + cx] + p1g[rb + cx];
        float va = p0v[rb + cx] + p1v[rb + cx];
        float sv = ga / (1.0f + expf(-ga)) * va;
        f[p] = sv; ss += sv * sv;
    }
    __shared__ float red[256];
    red[t] = ss; __syncthreads();
    for (int s2 = 128; s2 > 0; s2 >>= 1) { if (t < s2) red[t] += red[t + s2]; __syncthreads(); }
    float sc = rsqrtf(red[0] / (float)Dz + 1e-6f);
#pragma unroll
    for (int p = 0; p < 8; ++p) { int cx = t + p * 256; o[cx] = __float2bfloat16(f[p] * sc * w_np[cx]); }
}

// ---------------------------------------------------------------------------
static GOp gop(const void* A, const void* B, void* C, const float* add,
               int K, int lda, int ldb, int ldc, int nbh, int nb, int gx, int gy,
               long long sAb, long long sAh, long long sBb, long long sBh,
               long long sCb, long long sCh, int flags) {
    GOp o;
    o.A = A; o.B = B; o.C = C; o.add = add;
    o.sAb = sAb; o.sAh = sAh; o.sBb = sBb; o.sBh = sBh; o.sCb = sCb; o.sCh = sCh;
    o.K = K; o.lda = lda; o.ldb = ldb; o.ldc = ldc; o.nbh = nbh;
    o.gx = gx; o.gy = gy; o.flags = flags;
    o.tileEnd = (flags & 32) ? gx * gy : nb * gx * gy;  // count; prefixed later
    return o;
}

static void launch_multi(hipStream_t st, GOp* ops, int n) {
    GArgs ga; ga.n = n;
    int acc = 0;
    for (int i = 0; i < n; ++i) { acc += ops[i].tileEnd; ga.op[i] = ops[i]; ga.op[i].tileEnd = acc; }
    hipLaunchKernelGGL(gemm_multi, dim3(acc), dim3(256), 0, st, ga);
}

static void launch_256(hipStream_t st, GOp* ops, int n) {
    GArgs ga; ga.n = n;
    int acc = 0;
    for (int i = 0; i < n; ++i) { acc += ops[i].tileEnd; ga.op[i] = ops[i]; ga.op[i].tileEnd = acc; }
    hipLaunchKernelGGL(gemm_256, dim3(acc), dim3(512), 0, st, ga);
}

extern "C" void kernel_launch(void* const* d_in, const int* in_sizes, int n_in,
                              void* d_out, int out_size, void* d_ws, size_t ws_size,
                              hipStream_t stream) {
    const float* x     = (const float*)d_in[0];
    const float* w_in  = (const float*)d_in[1];
    const float* wc1   = (const float*)d_in[6];
    const float* bc1   = (const float*)d_in[7];
    const float* wc2   = (const float*)d_in[8];
    const float* bc2   = (const float*)d_in[9];
    const float* wq    = (const float*)d_in[10];
    const float* wk    = (const float*)d_in[11];
    const float* wv    = (const float*)d_in[12];
    const float* wo    = (const float*)d_in[13];
    const float* w_nc  = (const float*)d_in[14];
    const float* w_ns  = (const float*)d_in[15];
    const float* w_fgv = (const float*)d_in[16];
    const float* w_np  = (const float*)d_in[17];
    const float* w_out = (const float*)d_in[18];
    float* out = (float*)d_out;

    const size_t MB = 1ull << 20;
    char* W = (char*)d_ws;
    __hip_bfloat16* xn_bf    = (__hip_bfloat16*)(W + 0 * MB);
    __hip_bfloat16* kv_bf    = (__hip_bfloat16*)(W + 8 * MB);
    __hip_bfloat16* cheby_bf = (__hip_bfloat16*)(W + 16 * MB);
    __hip_bfloat16* q_bf     = (__hip_bfloat16*)(W + 24 * MB);
    __hip_bfloat16* k_bf     = (__hip_bfloat16*)(W + 32 * MB);
    __hip_bfloat16* vT_bf    = (__hip_bfloat16*)(W + 40 * MB);
    __hip_bfloat16* o_bf     = (__hip_bfloat16*)(W + 48 * MB);
    __hip_bfloat16* scores   = (__hip_bfloat16*)(W + 56 * MB);   // 32MB
    __hip_bfloat16* wq_t     = (__hip_bfloat16*)(W + 88 * MB);
    __hip_bfloat16* wk_t     = (__hip_bfloat16*)(W + 96 * MB);
    __hip_bfloat16* wv_t     = (__hip_bfloat16*)(W + 104 * MB);
    __hip_bfloat16* wo_t     = (__hip_bfloat16*)(W + 112 * MB);
    __hip_bfloat16* wout_t   = (__hip_bfloat16*)(W + 120 * MB);
    // lifetime reuse (scores region becomes wfgv_t only AFTER PV has consumed it)
    __hip_bfloat16* wfgv_t   = (__hip_bfloat16*)(W + 56 * MB);
    __hip_bfloat16* slr_bf   = (__hip_bfloat16*)(W + 0 * MB);    // xn dead
    __hip_bfloat16* hcat_bf  = (__hip_bfloat16*)(W + 24 * MB);   // q,k dead (16MB)
    __hip_bfloat16* fused_bf = (__hip_bfloat16*)(W + 16 * MB);   // cheby dead after L12
    // gv split-K fp32 partials (16MB each), in regions dead at L13:
    float* p0g = (float*)(W + 0 * MB);    // slr dead after L12
    float* p0v = (float*)(W + 40 * MB);   // vT dead after L10, o dead after L11
    float* p1g = (float*)(W + 88 * MB);   // wq_t dead after L8
    float* p1v = (float*)(W + 104 * MB);  // wv_t dead after L7, wo_t dead after L11
    float* xmp   = (float*)(W + 128 * MB);                       // 8*B*D
    float* hbuf  = xmp + 65536;
    float* cbuf  = hbuf + 2048;

    const int BS = Bz * Sz;
    const long long SD = (long long)Sz * Dz;
    const long long SS = (long long)Sz * Sz;

    // L1: five 2048x2048 weight transposes in one launch (128x128 tiles)
    {
        GOp ops[5];
        const float* srcs[5] = {wq, wk, wv, wo, w_out};
        __hip_bfloat16* dsts[5] = {wq_t, wk_t, wv_t, wo_t, wout_t};
        for (int i = 0; i < 5; ++i)
            ops[i] = gop(srcs[i], nullptr, dsts[i], nullptr, Dz, Dz, 0, Dz,
                         1, 1, 16, 16, 0, 0, 0, 0, 0, 0, 32);
        launch_multi(stream, ops, 5);
    }
    // L2: xn = rmsnorm(x)
    hipLaunchKernelGGL(rmsnorm_kernel, dim3(BS), dim3(256), 0, stream, x, w_in, xn_bf);
    // L3-L5: coeff path
    hipLaunchKernelGGL(xmean_p1, dim3(256), dim3(256), 0, stream, xn_bf, xmp);
    hipLaunchKernelGGL(mlp1_kernel, dim3(64), dim3(256), 0, stream, xmp, wc1, bc1, hbuf);
    hipLaunchKernelGGL(coeffs_kernel, dim3(512), dim3(256), 0, stream, hbuf, wc2, bc2, cbuf);
    // L6: cheby + kv_src
    hipLaunchKernelGGL(cheby_kernel, dim3(BS), dim3(256), 0, stream, xn_bf, cbuf, cheby_bf, kv_bf);
    // L7: q, k, vT via 256^2 GEMM (64+64+64 = 192 blocks)
    {
        GOp ops[3];
        ops[0] = gop(xn_bf, wq_t, q_bf, nullptr, Dz, Dz, Dz, Dz, 1, 1, 8, 8,
                     0, 0, 0, 0, 0, 0, 1);
        ops[1] = gop(kv_bf, wk_t, k_bf, nullptr, Dz, Dz, Dz, Dz, 1, 1, 8, 8,
                     0, 0, 0, 0, 0, 0, 1);
        ops[2] = gop(wv_t, kv_bf, vT_bf, nullptr, Dz, Dz, Dz, Sz, 1, Bz, 2, 8,
                     0, 0, SD, 0, (long long)Dz * Sz, 0, 1);
        launch_256(stream, ops, 3);
    }
    // L8: scores = q@k^T, scale+mask epilogue, skip masked tiles (legacy kernel)
    {
        GOp op = gop(q_bf, k_bf, scores, nullptr, AHDz, Dz, Dz, Sz, AHz, Bz * AHz, 4, 4,
                     SD, AHDz, SD, AHDz, (long long)AHz * SS, SS, 1 | 4);
        launch_multi(stream, &op, 1);
    }
    // L9: softmax (applies causal mask)
    hipLaunchKernelGGL(softmax_kernel, dim3(Bz * AHz * Sz), dim3(128), 0, stream, scores);
    // L10: PV alone (reads scores — nothing may write the scores region here!)
    {
        GOp op = gop(scores, vT_bf, o_bf, nullptr, Sz, Sz, Sz, Dz, AHz, Bz * AHz, 1, 4,
                     (long long)AHz * SS, SS, (long long)Dz * Sz, 128LL * Sz,
                     SD, 128, 1 | 8);
        launch_multi(stream, &op, 1);
    }
    // L11: slr = o @ wo (legacy, full-chip 256 blocks) + wfgv transpose
    // (128x128 tiles, 1024 blocks) in ONE launch so the memory-bound
    // transpose overlaps the compute-bound GEMM
    {
        GOp ops[2];
        ops[0] = gop(o_bf, wo_t, slr_bf, nullptr, Dz, Dz, Dz, Dz, 1, 1, 16, 16,
                     0, 0, 0, 0, 0, 0, 1);
        ops[1] = gop(w_fgv, nullptr, wfgv_t, nullptr, 2 * Dz, 2 * Dz, 0, 2 * Dz,
                     1, 1, 32, 32, 0, 0, 0, 0, 0, 0, 32);
        launch_multi(stream, ops, 2);
    }
    // L12: hcat
    hipLaunchKernelGGL(hcat_kernel, dim3(BS), dim3(256), 0, stream, cheby_bf, slr_bf, w_nc, w_ns, hcat_bf);
    // L13: gv = hcat @ w_fgv via 256^2 GEMM, split 4 ways (K-half x gate/value
    // N-half) = 4 x 64 = 256 blocks (exact chip fill); fp32 partials, the
    // K-reduction folds into fusedgate2.
    {
        const unsigned short* hc = (const unsigned short*)hcat_bf;
        const unsigned short* wf = (const unsigned short*)wfgv_t;
        GOp ops[4];
        ops[0] = gop(hc,        wf,                      p0g, nullptr, Dz, 2 * Dz, 2 * Dz, Dz,
                     1, 1, 8, 8, 0, 0, 0, 0, 0, 0, 0);
        ops[1] = gop(hc,        wf + 2048LL * 4096,      p0v, nullptr, Dz, 2 * Dz, 2 * Dz, Dz,
                     1, 1, 8, 8, 0, 0, 0, 0, 0, 0, 0);
        ops[2] = gop(hc + 2048, wf + 2048,               p1g, nullptr, Dz, 2 * Dz, 2 * Dz, Dz,
                     1, 1, 8, 8, 0, 0, 0, 0, 0, 0, 0);
        ops[3] = gop(hc + 2048, wf + 2048LL * 4096 + 2048, p1v, nullptr, Dz, 2 * Dz, 2 * Dz, Dz,
                     1, 1, 8, 8, 0, 0, 0, 0, 0, 0, 0);
        launch_256(stream, ops, 4);
    }
    // L14: fused gate (+ gv K-reduction)
    hipLaunchKernelGGL(fusedgate2_kernel, dim3(BS), dim3(256), 0, stream,
                       p0g, p0v, p1g, p1v, w_np, fused_bf);
    // L15: out = x + fused @ w_out (legacy, full-chip 256 blocks)
    {
        GOp op = gop(fused_bf, wout_t, out, x, Dz, Dz, Dz, Dz, 1, 1, 16, 16,
                     0, 0, 0, 0, 0, 0, 2);
        launch_multi(stream, &op, 1);
    }
}